// Round 3
// baseline (1040.081 us; speedup 1.0000x reference)
//
#include <hip/hip_runtime.h>

typedef unsigned short u16;
typedef unsigned int u32;
typedef __attribute__((ext_vector_type(8))) short short8;
typedef __attribute__((ext_vector_type(8))) _Float16 half8;
typedef __attribute__((ext_vector_type(2))) _Float16 half2v;
typedef __attribute__((ext_vector_type(2))) __fp16 fp16x2;
typedef __attribute__((ext_vector_type(4))) float floatx4;

__device__ __forceinline__ u16 f2h(float f){ _Float16 h = (_Float16)f; return __builtin_bit_cast(u16, h); }
__device__ __forceinline__ float h2f(u16 h){ return (float)__builtin_bit_cast(_Float16, h); }
__device__ __forceinline__ u32 pkrtz(float a, float b){
  fp16x2 h = __builtin_amdgcn_cvt_pkrtz(a, b);
  return __builtin_bit_cast(u32, h);
}

// ---------------- prep: plane transpose [C=32][HW] f32 -> [HW][C] f16
__global__ void ptrans_kernel(const float* __restrict__ src, u16* __restrict__ dst, int HW){
  __shared__ float tile[32][257];
  const int t = threadIdx.x;
  const size_t hw0 = (size_t)blockIdx.x * 256;
  #pragma unroll
  for (int c = 0; c < 32; c++) tile[c][t] = src[(size_t)c*HW + hw0 + t];
  __syncthreads();
  u32* d32 = (u32*)(dst + hw0*32);
  #pragma unroll
  for (int i = 0; i < 16; i++){
    int idx = i*512 + t*2;
    int j = idx >> 5, cc = idx & 31;
    u32 lo = f2h(tile[cc][j]);
    u32 hi = f2h(tile[cc+1][j]);
    d32[i*256 + t] = lo | (hi << 16);
  }
}

// ---------------- prep: weight transpose+convert: dst[m][n][k] = f16(src[m][k][n])
__global__ void wconv_kernel(const float* __restrict__ src, u16* __restrict__ dst,
                             int fin, int fout, int total){
  int t = blockIdx.x*256 + threadIdx.x;
  if (t >= total) return;
  int per = fin * fout;
  int m = t / per, rem = t - m*per;
  int nn = rem / fin, kk = rem - nn*fin;
  dst[t] = f2h(src[(size_t)m*per + (size_t)kk*fout + nn]);
}

// ---------------- interpolation
struct PlanePtrs { const void* p[9]; };

__device__ __forceinline__ void load8h(const u16* p, float* f){
  half8 h = *(const half8*)p;
  #pragma unroll
  for (int e=0;e<8;e++) f[e] = (float)h[e];
}

template<bool TR>
__global__ void interp_kernel(const float* __restrict__ pts, const float* __restrict__ aabb,
                              PlanePtrs pp, u16* __restrict__ feats, int N)
{
  int n = blockIdx.x*256 + threadIdx.x;
  if (n >= N) return;
  float xn[3];
  #pragma unroll
  for (int d=0; d<3; d++){
    float lo = aabb[d], hi = aabb[3+d];
    xn[d] = (pts[(size_t)n*3 + d] - lo) * (2.0f/(hi - lo)) - 1.0f;
  }
  const int c0s[3] = {0,0,1};
  const int c1s[3] = {1,2,2};
  #pragma unroll
  for (int s=0; s<3; s++){
    const int R = 128 << s;
    float prod[32];
    #pragma unroll
    for (int p=0; p<3; p++){
      float fx = (xn[c0s[p]] + 1.0f) * 0.5f * (float)(R-1);
      float fy = (xn[c1s[p]] + 1.0f) * 0.5f * (float)(R-1);
      float fx0 = fminf(fmaxf(floorf(fx), 0.0f), (float)(R-2));
      float fy0 = fminf(fmaxf(floorf(fy), 0.0f), (float)(R-2));
      int x0 = (int)fx0, y0 = (int)fy0;
      float wx = fx - fx0, wy = fy - fy0;
      float w00 = (1.0f-wx)*(1.0f-wy), w01 = wx*(1.0f-wy);
      float w10 = (1.0f-wx)*wy,        w11 = wx*wy;
      if constexpr (TR){
        const u16* base = (const u16*)pp.p[s*3 + p];
        const u16* b00 = base + ((size_t)y0*R + x0)*32;
        const u16* b10 = b00 + (size_t)R*32;
        #pragma unroll
        for (int v=0; v<4; v++){
          float f00[8], f01[8], f10[8], f11[8];
          load8h(b00 + v*8,      f00);
          load8h(b00 + 32 + v*8, f01);
          load8h(b10 + v*8,      f10);
          load8h(b10 + 32 + v*8, f11);
          #pragma unroll
          for (int e=0; e<8; e++){
            int c = v*8 + e;
            float val = f00[e]*w00 + f01[e]*w01 + f10[e]*w10 + f11[e]*w11;
            prod[c] = (p == 0) ? val : prod[c]*val;
          }
        }
      } else {
        const size_t HW = (size_t)R*R;
        const float* b00f = (const float*)pp.p[s*3+p] + (size_t)y0*R + x0;
        #pragma unroll 4
        for (int c=0; c<32; c++){
          const float* q = b00f + (size_t)c*HW;
          float val = q[0]*w00 + q[1]*w01 + q[R]*w10 + q[R+1]*w11;
          prod[c] = (p == 0) ? val : prod[c]*val;
        }
      }
    }
    #pragma unroll
    for (int v=0; v<4; v++){
      short8 pk;
      #pragma unroll
      for (int e=0; e<8; e++) pk[e] = (short)f2h(prod[v*8+e]);
      *(short8*)(feats + (size_t)n*96 + s*32 + v*8) = pk;
    }
  }
}

// ---------------- fused MLP (fp16 MFMA)
// X in LDS: [64 rows][256 cols] f16, byte addr = (row*512 + col*2) ^ ((row&7)<<4)
__device__ __forceinline__ void mm_tile(const u16* X, const u16* __restrict__ WT,
                                        int K, int colbase, int lane, floatx4 acc[4][4])
{
  const int lr = lane & 15, lg = lane >> 4;
  floatx4 zf = {0.0f, 0.0f, 0.0f, 0.0f};
  #pragma unroll
  for (int rf=0; rf<4; rf++)
    #pragma unroll
    for (int cf=0; cf<4; cf++)
      acc[rf][cf] = zf;
  const int ksteps = K >> 5;
  #pragma unroll
  for (int ks=0; ks<ksteps; ks++){
    half8 a[4], b[4];
    #pragma unroll
    for (int rf=0; rf<4; rf++){
      int row = rf*16 + lr;
      int byt = (row*512 + (ks*32 + lg*8)*2) ^ ((row & 7) << 4);
      a[rf] = *(const half8*)((const char*)X + byt);
    }
    #pragma unroll
    for (int cf=0; cf<4; cf++){
      int col = colbase + cf*16 + lr;
      b[cf] = *(const half8*)(WT + (size_t)col*K + ks*32 + lg*8);
    }
    #pragma unroll
    for (int rf=0; rf<4; rf++)
      #pragma unroll
      for (int cf=0; cf<4; cf++)
        acc[rf][cf] = __builtin_amdgcn_mfma_f32_16x16x32_f16(a[rf], b[cf], acc[rf][cf], 0, 0, 0);
  }
}

__global__ __launch_bounds__(256, 3) void mlp_kernel(
    const u16* __restrict__ feats,
    const u16* __restrict__ l0T, const u16* __restrict__ resT, const u16* __restrict__ l1T,
    const float* __restrict__ l0_b, const float* __restrict__ res_b, const float* __restrict__ l1_b,
    float* __restrict__ out)
{
  __shared__ u16 X[64*256];
  const int tid = threadIdx.x;
  const int wave = tid >> 6, lane = tid & 63;
  const int lr = lane & 15, lg = lane >> 4;
  const int n0 = blockIdx.x * 64;
  const int colbase = wave * 64;

  // stage feats tile: 64 rows x 96 cols f16
  #pragma unroll
  for (int i=0; i<3; i++){
    int id = tid + i*256;
    int row = id / 12, sub = id - row*12;
    short8 v = *(const short8*)(feats + (size_t)(n0+row)*96 + sub*8);
    int byt = (row*512 + sub*16) ^ ((row & 7) << 4);
    *(short8*)((char*)X + byt) = v;
  }
  __syncthreads();

  floatx4 acc[4][4];
  u32 pk[4][4][2];   // this wave's current x tile, packed f16 pairs (rows r=0,1 | r=2,3)

  // ---- L0: K=96, no activation
  mm_tile(X, l0T, 96, colbase, lane, acc);
  __syncthreads();
  #pragma unroll
  for (int cf=0; cf<4; cf++){
    int col = colbase + cf*16 + lr;
    float bb = l0_b[col];
    #pragma unroll
    for (int rf=0; rf<4; rf++){
      float v0 = acc[rf][cf][0] + bb, v1 = acc[rf][cf][1] + bb;
      float v2 = acc[rf][cf][2] + bb, v3 = acc[rf][cf][3] + bb;
      u32 p0 = pkrtz(v0, v1), p1 = pkrtz(v2, v3);
      pk[rf][cf][0] = p0; pk[rf][cf][1] = p1;
      int row = rf*16 + lg*4;
      int b0y = ((row+0)*512 + col*2) ^ (((row+0)&7)<<4);
      int b1y = ((row+1)*512 + col*2) ^ (((row+1)&7)<<4);
      int b2y = ((row+2)*512 + col*2) ^ (((row+2)&7)<<4);
      int b3y = ((row+3)*512 + col*2) ^ (((row+3)&7)<<4);
      *(u16*)((char*)X + b0y) = (u16)p0;
      *(u16*)((char*)X + b1y) = (u16)(p0 >> 16);
      *(u16*)((char*)X + b2y) = (u16)p1;
      *(u16*)((char*)X + b3y) = (u16)(p1 >> 16);
    }
  }
  __syncthreads();

  // ---- 3 ResBlocks
  for (int rb=0; rb<3; rb++){
    const u16* W0 = resT + (size_t)(rb*3+0)*65536;
    const u16* W1 = resT + (size_t)(rb*3+1)*65536;
    const u16* W2 = resT + (size_t)(rb*3+2)*65536;
    const float* b0 = res_b + (rb*3+0)*256;
    const float* b1 = res_b + (rb*3+1)*256;
    const float* b2 = res_b + (rb*3+2)*256;

    // res = x + relu(x@W0+b0): x comes from pk (no LDS re-read)
    mm_tile(X, W0, 256, colbase, lane, acc);
    __syncthreads();
    #pragma unroll
    for (int cf=0; cf<4; cf++){
      int col = colbase + cf*16 + lr;
      float bb = b0[col];
      #pragma unroll
      for (int rf=0; rf<4; rf++){
        half2v x01 = __builtin_bit_cast(half2v, pk[rf][cf][0]);
        half2v x23 = __builtin_bit_cast(half2v, pk[rf][cf][1]);
        float v0 = (float)x01[0] + fmaxf(acc[rf][cf][0] + bb, 0.0f);
        float v1 = (float)x01[1] + fmaxf(acc[rf][cf][1] + bb, 0.0f);
        float v2 = (float)x23[0] + fmaxf(acc[rf][cf][2] + bb, 0.0f);
        float v3 = (float)x23[1] + fmaxf(acc[rf][cf][3] + bb, 0.0f);
        u32 p0 = pkrtz(v0, v1), p1 = pkrtz(v2, v3);
        pk[rf][cf][0] = p0; pk[rf][cf][1] = p1;   // pk now holds res
        int row = rf*16 + lg*4;
        int b0y = ((row+0)*512 + col*2) ^ (((row+0)&7)<<4);
        int b1y = ((row+1)*512 + col*2) ^ (((row+1)&7)<<4);
        int b2y = ((row+2)*512 + col*2) ^ (((row+2)&7)<<4);
        int b3y = ((row+3)*512 + col*2) ^ (((row+3)&7)<<4);
        *(u16*)((char*)X + b0y) = (u16)p0;
        *(u16*)((char*)X + b1y) = (u16)(p0 >> 16);
        *(u16*)((char*)X + b2y) = (u16)p1;
        *(u16*)((char*)X + b3y) = (u16)(p1 >> 16);
      }
    }
    __syncthreads();

    // x = relu(res@W1+b1) -> X only
    mm_tile(X, W1, 256, colbase, lane, acc);
    __syncthreads();
    #pragma unroll
    for (int cf=0; cf<4; cf++){
      int col = colbase + cf*16 + lr;
      float bb = b1[col];
      #pragma unroll
      for (int rf=0; rf<4; rf++){
        float v0 = fmaxf(acc[rf][cf][0] + bb, 0.0f), v1 = fmaxf(acc[rf][cf][1] + bb, 0.0f);
        float v2 = fmaxf(acc[rf][cf][2] + bb, 0.0f), v3 = fmaxf(acc[rf][cf][3] + bb, 0.0f);
        u32 p0 = pkrtz(v0, v1), p1 = pkrtz(v2, v3);
        int row = rf*16 + lg*4;
        int b0y = ((row+0)*512 + col*2) ^ (((row+0)&7)<<4);
        int b1y = ((row+1)*512 + col*2) ^ (((row+1)&7)<<4);
        int b2y = ((row+2)*512 + col*2) ^ (((row+2)&7)<<4);
        int b3y = ((row+3)*512 + col*2) ^ (((row+3)&7)<<4);
        *(u16*)((char*)X + b0y) = (u16)p0;
        *(u16*)((char*)X + b1y) = (u16)(p0 >> 16);
        *(u16*)((char*)X + b2y) = (u16)p1;
        *(u16*)((char*)X + b3y) = (u16)(p1 >> 16);
      }
    }
    __syncthreads();

    // x = relu(x@W2+b2) + res(pk)
    mm_tile(X, W2, 256, colbase, lane, acc);
    __syncthreads();
    #pragma unroll
    for (int cf=0; cf<4; cf++){
      int col = colbase + cf*16 + lr;
      float bb = b2[col];
      #pragma unroll
      for (int rf=0; rf<4; rf++){
        half2v r01 = __builtin_bit_cast(half2v, pk[rf][cf][0]);
        half2v r23 = __builtin_bit_cast(half2v, pk[rf][cf][1]);
        float v0 = fmaxf(acc[rf][cf][0] + bb, 0.0f) + (float)r01[0];
        float v1 = fmaxf(acc[rf][cf][1] + bb, 0.0f) + (float)r01[1];
        float v2 = fmaxf(acc[rf][cf][2] + bb, 0.0f) + (float)r23[0];
        float v3 = fmaxf(acc[rf][cf][3] + bb, 0.0f) + (float)r23[1];
        u32 p0 = pkrtz(v0, v1), p1 = pkrtz(v2, v3);
        pk[rf][cf][0] = p0; pk[rf][cf][1] = p1;   // pk now holds new x
        int row = rf*16 + lg*4;
        int b0y = ((row+0)*512 + col*2) ^ (((row+0)&7)<<4);
        int b1y = ((row+1)*512 + col*2) ^ (((row+1)&7)<<4);
        int b2y = ((row+2)*512 + col*2) ^ (((row+2)&7)<<4);
        int b3y = ((row+3)*512 + col*2) ^ (((row+3)&7)<<4);
        *(u16*)((char*)X + b0y) = (u16)p0;
        *(u16*)((char*)X + b1y) = (u16)(p0 >> 16);
        *(u16*)((char*)X + b2y) = (u16)p1;
        *(u16*)((char*)X + b3y) = (u16)(p1 >> 16);
      }
    }
    __syncthreads();
  }

  // ---- final: 256 -> 16, sigmoid. Each wave: 16 rows x 16 cols.
  floatx4 accf = {0.0f, 0.0f, 0.0f, 0.0f};
  #pragma unroll
  for (int ks=0; ks<8; ks++){
    int row = wave*16 + lr;
    int byt = (row*512 + (ks*32 + lg*8)*2) ^ ((row&7)<<4);
    half8 a = *(const half8*)((const char*)X + byt);
    half8 b = *(const half8*)(l1T + (size_t)lr*256 + ks*32 + lg*8);
    accf = __builtin_amdgcn_mfma_f32_16x16x32_f16(a, b, accf, 0, 0, 0);
  }
  float bo = l1_b[lr];
  #pragma unroll
  for (int r=0; r<4; r++){
    int row = wave*16 + lg*4 + r;
    float v = accf[r] + bo;
    v = 1.0f / (1.0f + __expf(-v));
    out[(size_t)(n0+row)*16 + lr] = v;
  }
}

// ---------------- host
extern "C" void kernel_launch(void* const* d_in, const int* in_sizes, int n_in,
                              void* d_out, int out_size, void* d_ws, size_t ws_size,
                              hipStream_t stream)
{
  const float* pts  = (const float*)d_in[0];
  const float* aabb = (const float*)d_in[1];
  const float* l0_w = (const float*)d_in[11];
  const float* res_w= (const float*)d_in[13];
  const float* l1_w = (const float*)d_in[15];
  const float* l0_b = (const float*)d_in[12];
  const float* res_b= (const float*)d_in[14];
  const float* l1_b = (const float*)d_in[16];
  const int N = in_sizes[0] / 3;

  char* ws = (char*)d_ws;
  const size_t woff_l0  = 0;                          // 256*96*2
  const size_t woff_res = 49152;                      // 9*65536*2
  const size_t woff_l1  = woff_res + 9*65536*2;       // 16*256*2
  const size_t foff     = woff_l1 + 8192;             // feats: N*96*2
  const size_t poff     = foff + (size_t)N*96*2;      // f16 planes

  static const int HWs[3] = {128*128, 256*256, 512*512};
  size_t pel[9]; size_t tot = 0;
  for (int s=0;s<3;s++) for (int p=0;p<3;p++){ pel[s*3+p] = tot; tot += (size_t)HWs[s]*32; }

  const bool tr_mode = (ws_size >= poff + tot*2);

  // weights -> [out][in] f16
  wconv_kernel<<<(24576+255)/256,  256, 0, stream>>>(l0_w, (u16*)(ws+woff_l0), 96, 256, 24576);
  wconv_kernel<<<(589824+255)/256, 256, 0, stream>>>(res_w,(u16*)(ws+woff_res),256, 256, 589824);
  wconv_kernel<<<(4096+255)/256,   256, 0, stream>>>(l1_w, (u16*)(ws+woff_l1), 256, 16,  4096);

  PlanePtrs pp;
  if (tr_mode){
    u16* pbase = (u16*)(ws + poff);
    for (int i=0;i<9;i++){
      int s = i/3;
      ptrans_kernel<<<HWs[s]/256, 256, 0, stream>>>((const float*)d_in[2+i], pbase + pel[i], HWs[s]);
      pp.p[i] = pbase + pel[i];
    }
    interp_kernel<true><<<(N+255)/256, 256, 0, stream>>>(pts, aabb, pp, (u16*)(ws+foff), N);
  } else {
    for (int i=0;i<9;i++) pp.p[i] = d_in[2+i];
    interp_kernel<false><<<(N+255)/256, 256, 0, stream>>>(pts, aabb, pp, (u16*)(ws+foff), N);
  }

  mlp_kernel<<<N/64, 256, 0, stream>>>((const u16*)(ws+foff),
      (const u16*)(ws+woff_l0), (const u16*)(ws+woff_res), (const u16*)(ws+woff_l1),
      l0_b, res_b, l1_b, (float*)d_out);
}

// Round 4
// 807.337 us; speedup vs baseline: 1.2883x; 1.2883x over previous
//
#include <hip/hip_runtime.h>

typedef unsigned short u16;
typedef unsigned int u32;
typedef __attribute__((ext_vector_type(8))) short short8;
typedef __attribute__((ext_vector_type(8))) _Float16 half8;
typedef __attribute__((ext_vector_type(2))) _Float16 half2v;
typedef __attribute__((ext_vector_type(2))) __fp16 fp16x2;
typedef __attribute__((ext_vector_type(4))) float floatx4;

__device__ __forceinline__ u16 f2h(float f){ _Float16 h = (_Float16)f; return __builtin_bit_cast(u16, h); }
__device__ __forceinline__ u32 pkrtz(float a, float b){
  fp16x2 h = __builtin_amdgcn_cvt_pkrtz(a, b);
  return __builtin_bit_cast(u32, h);
}

// ---------------- prep: plane transpose [C=32][HW] f32 -> [HW][C] f16
__global__ void ptrans_kernel(const float* __restrict__ src, u16* __restrict__ dst, int HW){
  __shared__ float tile[32][257];
  const int t = threadIdx.x;
  const size_t hw0 = (size_t)blockIdx.x * 256;
  #pragma unroll
  for (int c = 0; c < 32; c++) tile[c][t] = src[(size_t)c*HW + hw0 + t];
  __syncthreads();
  u32* d32 = (u32*)(dst + hw0*32);
  #pragma unroll
  for (int i = 0; i < 16; i++){
    int idx = i*512 + t*2;
    int j = idx >> 5, cc = idx & 31;
    u32 lo = f2h(tile[cc][j]);
    u32 hi = f2h(tile[cc+1][j]);
    d32[i*256 + t] = lo | (hi << 16);
  }
}

// ---------------- prep: weights -> MFMA-fragment order f16
// Logical WT[n][k] = src[m][k][n]; stored as dst[m][ct][ks][lane][e]:
//   col = ct*16 + (lane&15), k = ks*32 + (lane>>4)*8 + e
// so a wave's b-fragment load for (ct,ks) is one contiguous 1KB burst.
__global__ void wconv_kernel(const float* __restrict__ src, u16* __restrict__ dst,
                             int fin, int fout, int total){
  int t = blockIdx.x*256 + threadIdx.x;
  if (t >= total) return;
  int per = fin * fout;
  int m = t / per, r = t - m*per;
  int KS = fin >> 5;
  int e = r & 7;
  int lane = (r >> 3) & 63;
  int fs = r >> 9;                 // fragment-slot: ct*KS + ks
  int ks = fs % KS, ct = fs / KS;
  int col = ct*16 + (lane & 15);
  int k   = ks*32 + (lane >> 4)*8 + e;
  dst[t] = f2h(src[(size_t)m*per + (size_t)k*fout + col]);
}

// ---------------- interpolation
struct PlanePtrs { const void* p[9]; };

__device__ __forceinline__ void load8h(const u16* p, float* f){
  half8 h = *(const half8*)p;
  #pragma unroll
  for (int e=0;e<8;e++) f[e] = (float)h[e];
}

template<bool TR>
__global__ void interp_kernel(const float* __restrict__ pts, const float* __restrict__ aabb,
                              PlanePtrs pp, u16* __restrict__ feats, int N)
{
  int n = blockIdx.x*256 + threadIdx.x;
  if (n >= N) return;
  float xn[3];
  #pragma unroll
  for (int d=0; d<3; d++){
    float lo = aabb[d], hi = aabb[3+d];
    xn[d] = (pts[(size_t)n*3 + d] - lo) * (2.0f/(hi - lo)) - 1.0f;
  }
  const int c0s[3] = {0,0,1};
  const int c1s[3] = {1,2,2};
  #pragma unroll
  for (int s=0; s<3; s++){
    const int R = 128 << s;
    float prod[32];
    #pragma unroll
    for (int p=0; p<3; p++){
      float fx = (xn[c0s[p]] + 1.0f) * 0.5f * (float)(R-1);
      float fy = (xn[c1s[p]] + 1.0f) * 0.5f * (float)(R-1);
      float fx0 = fminf(fmaxf(floorf(fx), 0.0f), (float)(R-2));
      float fy0 = fminf(fmaxf(floorf(fy), 0.0f), (float)(R-2));
      int x0 = (int)fx0, y0 = (int)fy0;
      float wx = fx - fx0, wy = fy - fy0;
      float w00 = (1.0f-wx)*(1.0f-wy), w01 = wx*(1.0f-wy);
      float w10 = (1.0f-wx)*wy,        w11 = wx*wy;
      if constexpr (TR){
        const u16* base = (const u16*)pp.p[s*3 + p];
        const u16* b00 = base + ((size_t)y0*R + x0)*32;
        const u16* b10 = b00 + (size_t)R*32;
        #pragma unroll
        for (int v=0; v<4; v++){
          float f00[8], f01[8], f10[8], f11[8];
          load8h(b00 + v*8,      f00);
          load8h(b00 + 32 + v*8, f01);
          load8h(b10 + v*8,      f10);
          load8h(b10 + 32 + v*8, f11);
          #pragma unroll
          for (int e=0; e<8; e++){
            int c = v*8 + e;
            float val = f00[e]*w00 + f01[e]*w01 + f10[e]*w10 + f11[e]*w11;
            prod[c] = (p == 0) ? val : prod[c]*val;
          }
        }
      } else {
        const size_t HW = (size_t)R*R;
        const float* b00f = (const float*)pp.p[s*3+p] + (size_t)y0*R + x0;
        #pragma unroll 4
        for (int c=0; c<32; c++){
          const float* q = b00f + (size_t)c*HW;
          float val = q[0]*w00 + q[1]*w01 + q[R]*w10 + q[R+1]*w11;
          prod[c] = (p == 0) ? val : prod[c]*val;
        }
      }
    }
    #pragma unroll
    for (int v=0; v<4; v++){
      short8 pk;
      #pragma unroll
      for (int e=0; e<8; e++) pk[e] = (short)f2h(prod[v*8+e]);
      *(short8*)(feats + (size_t)n*96 + s*32 + v*8) = pk;
    }
  }
}

// ---------------- fused MLP (fp16 MFMA)
// X in LDS: [64 rows][256 cols] f16, byte addr = (row*512 + col*2) ^ ((row&7)<<4)
// Weights in fragment order: WTs[(ct*KSTEPS + ks)*512 + lane*8 + e]
template<int KSTEPS>
__device__ __forceinline__ void mm_tile(const u16* X, const u16* __restrict__ WTs,
                                        int ctbase, int lane, floatx4 acc[4][4])
{
  const int lr = lane & 15, lg = lane >> 4;
  #pragma unroll
  for (int rf=0; rf<4; rf++)
    #pragma unroll
    for (int cf=0; cf<4; cf++)
      acc[rf][cf] = (floatx4){0.0f, 0.0f, 0.0f, 0.0f};
  half8 b[4], bn[4];
  #pragma unroll
  for (int cf=0; cf<4; cf++)
    b[cf] = *(const half8*)(WTs + ((size_t)((ctbase+cf)*KSTEPS)*64 + lane)*8);
  #pragma unroll
  for (int ks=0; ks<KSTEPS; ks++){
    half8 a[4];
    #pragma unroll
    for (int rf=0; rf<4; rf++){
      int row = rf*16 + lr;
      int byt = (row*512 + (ks*32 + lg*8)*2) ^ ((row & 7) << 4);
      a[rf] = *(const half8*)((const char*)X + byt);
    }
    if (ks+1 < KSTEPS){
      #pragma unroll
      for (int cf=0; cf<4; cf++)
        bn[cf] = *(const half8*)(WTs + ((size_t)((ctbase+cf)*KSTEPS + ks+1)*64 + lane)*8);
    }
    #pragma unroll
    for (int rf=0; rf<4; rf++)
      #pragma unroll
      for (int cf=0; cf<4; cf++)
        acc[rf][cf] = __builtin_amdgcn_mfma_f32_16x16x32_f16(a[rf], b[cf], acc[rf][cf], 0, 0, 0);
    #pragma unroll
    for (int cf=0; cf<4; cf++) b[cf] = bn[cf];
  }
}

__global__ __launch_bounds__(256, 2) void mlp_kernel(
    const u16* __restrict__ feats,
    const u16* __restrict__ l0T, const u16* __restrict__ resT, const u16* __restrict__ l1T,
    const float* __restrict__ l0_b, const float* __restrict__ res_b, const float* __restrict__ l1_b,
    float* __restrict__ out)
{
  __shared__ u16 X[64*256];
  const int tid = threadIdx.x;
  const int wave = tid >> 6, lane = tid & 63;
  const int lr = lane & 15, lg = lane >> 4;
  const int n0 = blockIdx.x * 64;
  const int ctbase = wave * 4;          // column-tile base (16 cols per ct)
  const int colbase = wave * 64;

  // stage feats tile: 64 rows x 96 cols f16
  #pragma unroll
  for (int i=0; i<3; i++){
    int id = tid + i*256;
    int row = id / 12, sub = id - row*12;
    short8 v = *(const short8*)(feats + (size_t)(n0+row)*96 + sub*8);
    int byt = (row*512 + sub*16) ^ ((row & 7) << 4);
    *(short8*)((char*)X + byt) = v;
  }
  __syncthreads();

  floatx4 acc[4][4];
  u32 pk[4][4][2];   // this wave's current x tile, packed f16 pairs (rows r=0,1 | r=2,3)

  // ---- L0: K=96, no activation
  mm_tile<3>(X, l0T, ctbase, lane, acc);
  __syncthreads();
  #pragma unroll
  for (int cf=0; cf<4; cf++){
    int col = colbase + cf*16 + lr;
    float bb = l0_b[col];
    #pragma unroll
    for (int rf=0; rf<4; rf++){
      float v0 = acc[rf][cf][0] + bb, v1 = acc[rf][cf][1] + bb;
      float v2 = acc[rf][cf][2] + bb, v3 = acc[rf][cf][3] + bb;
      u32 p0 = pkrtz(v0, v1), p1 = pkrtz(v2, v3);
      pk[rf][cf][0] = p0; pk[rf][cf][1] = p1;
      int row = rf*16 + lg*4;
      int b0y = ((row+0)*512 + col*2) ^ (((row+0)&7)<<4);
      int b1y = ((row+1)*512 + col*2) ^ (((row+1)&7)<<4);
      int b2y = ((row+2)*512 + col*2) ^ (((row+2)&7)<<4);
      int b3y = ((row+3)*512 + col*2) ^ (((row+3)&7)<<4);
      *(u16*)((char*)X + b0y) = (u16)p0;
      *(u16*)((char*)X + b1y) = (u16)(p0 >> 16);
      *(u16*)((char*)X + b2y) = (u16)p1;
      *(u16*)((char*)X + b3y) = (u16)(p1 >> 16);
    }
  }
  __syncthreads();

  // ---- 3 ResBlocks
  for (int rb=0; rb<3; rb++){
    const u16* W0 = resT + (size_t)(rb*3+0)*65536;
    const u16* W1 = resT + (size_t)(rb*3+1)*65536;
    const u16* W2 = resT + (size_t)(rb*3+2)*65536;
    const float* b0 = res_b + (rb*3+0)*256;
    const float* b1 = res_b + (rb*3+1)*256;
    const float* b2 = res_b + (rb*3+2)*256;

    // res = x + relu(x@W0+b0): x comes from pk (no LDS re-read)
    mm_tile<8>(X, W0, ctbase, lane, acc);
    __syncthreads();
    #pragma unroll
    for (int cf=0; cf<4; cf++){
      int col = colbase + cf*16 + lr;
      float bb = b0[col];
      #pragma unroll
      for (int rf=0; rf<4; rf++){
        half2v x01 = __builtin_bit_cast(half2v, pk[rf][cf][0]);
        half2v x23 = __builtin_bit_cast(half2v, pk[rf][cf][1]);
        float v0 = (float)x01[0] + fmaxf(acc[rf][cf][0] + bb, 0.0f);
        float v1 = (float)x01[1] + fmaxf(acc[rf][cf][1] + bb, 0.0f);
        float v2 = (float)x23[0] + fmaxf(acc[rf][cf][2] + bb, 0.0f);
        float v3 = (float)x23[1] + fmaxf(acc[rf][cf][3] + bb, 0.0f);
        u32 p0 = pkrtz(v0, v1), p1 = pkrtz(v2, v3);
        pk[rf][cf][0] = p0; pk[rf][cf][1] = p1;   // pk now holds res
        int row = rf*16 + lg*4;
        int b0y = ((row+0)*512 + col*2) ^ (((row+0)&7)<<4);
        int b1y = ((row+1)*512 + col*2) ^ (((row+1)&7)<<4);
        int b2y = ((row+2)*512 + col*2) ^ (((row+2)&7)<<4);
        int b3y = ((row+3)*512 + col*2) ^ (((row+3)&7)<<4);
        *(u16*)((char*)X + b0y) = (u16)p0;
        *(u16*)((char*)X + b1y) = (u16)(p0 >> 16);
        *(u16*)((char*)X + b2y) = (u16)p1;
        *(u16*)((char*)X + b3y) = (u16)(p1 >> 16);
      }
    }
    __syncthreads();

    // x = relu(res@W1+b1) -> X only
    mm_tile<8>(X, W1, ctbase, lane, acc);
    __syncthreads();
    #pragma unroll
    for (int cf=0; cf<4; cf++){
      int col = colbase + cf*16 + lr;
      float bb = b1[col];
      #pragma unroll
      for (int rf=0; rf<4; rf++){
        float v0 = fmaxf(acc[rf][cf][0] + bb, 0.0f), v1 = fmaxf(acc[rf][cf][1] + bb, 0.0f);
        float v2 = fmaxf(acc[rf][cf][2] + bb, 0.0f), v3 = fmaxf(acc[rf][cf][3] + bb, 0.0f);
        u32 p0 = pkrtz(v0, v1), p1 = pkrtz(v2, v3);
        int row = rf*16 + lg*4;
        int b0y = ((row+0)*512 + col*2) ^ (((row+0)&7)<<4);
        int b1y = ((row+1)*512 + col*2) ^ (((row+1)&7)<<4);
        int b2y = ((row+2)*512 + col*2) ^ (((row+2)&7)<<4);
        int b3y = ((row+3)*512 + col*2) ^ (((row+3)&7)<<4);
        *(u16*)((char*)X + b0y) = (u16)p0;
        *(u16*)((char*)X + b1y) = (u16)(p0 >> 16);
        *(u16*)((char*)X + b2y) = (u16)p1;
        *(u16*)((char*)X + b3y) = (u16)(p1 >> 16);
      }
    }
    __syncthreads();

    // x = relu(x@W2+b2) + res(pk)
    mm_tile<8>(X, W2, ctbase, lane, acc);
    __syncthreads();
    #pragma unroll
    for (int cf=0; cf<4; cf++){
      int col = colbase + cf*16 + lr;
      float bb = b2[col];
      #pragma unroll
      for (int rf=0; rf<4; rf++){
        half2v r01 = __builtin_bit_cast(half2v, pk[rf][cf][0]);
        half2v r23 = __builtin_bit_cast(half2v, pk[rf][cf][1]);
        float v0 = fmaxf(acc[rf][cf][0] + bb, 0.0f) + (float)r01[0];
        float v1 = fmaxf(acc[rf][cf][1] + bb, 0.0f) + (float)r01[1];
        float v2 = fmaxf(acc[rf][cf][2] + bb, 0.0f) + (float)r23[0];
        float v3 = fmaxf(acc[rf][cf][3] + bb, 0.0f) + (float)r23[1];
        u32 p0 = pkrtz(v0, v1), p1 = pkrtz(v2, v3);
        pk[rf][cf][0] = p0; pk[rf][cf][1] = p1;   // pk now holds new x
        int row = rf*16 + lg*4;
        int b0y = ((row+0)*512 + col*2) ^ (((row+0)&7)<<4);
        int b1y = ((row+1)*512 + col*2) ^ (((row+1)&7)<<4);
        int b2y = ((row+2)*512 + col*2) ^ (((row+2)&7)<<4);
        int b3y = ((row+3)*512 + col*2) ^ (((row+3)&7)<<4);
        *(u16*)((char*)X + b0y) = (u16)p0;
        *(u16*)((char*)X + b1y) = (u16)(p0 >> 16);
        *(u16*)((char*)X + b2y) = (u16)p1;
        *(u16*)((char*)X + b3y) = (u16)(p1 >> 16);
      }
    }
    __syncthreads();
  }

  // ---- final: 256 -> 16, sigmoid. Each wave: 16 rows x 16 cols.
  floatx4 accf = {0.0f, 0.0f, 0.0f, 0.0f};
  #pragma unroll
  for (int ks=0; ks<8; ks++){
    int row = wave*16 + lr;
    int byt = (row*512 + (ks*32 + lg*8)*2) ^ ((row&7)<<4);
    half8 a = *(const half8*)((const char*)X + byt);
    half8 b = *(const half8*)(l1T + ((size_t)ks*64 + lane)*8);
    accf = __builtin_amdgcn_mfma_f32_16x16x32_f16(a, b, accf, 0, 0, 0);
  }
  float bo = l1_b[lr];
  #pragma unroll
  for (int r=0; r<4; r++){
    int row = wave*16 + lg*4 + r;
    float v = accf[r] + bo;
    v = 1.0f / (1.0f + __expf(-v));
    out[(size_t)(n0+row)*16 + lr] = v;
  }
}

// ---------------- host
extern "C" void kernel_launch(void* const* d_in, const int* in_sizes, int n_in,
                              void* d_out, int out_size, void* d_ws, size_t ws_size,
                              hipStream_t stream)
{
  const float* pts  = (const float*)d_in[0];
  const float* aabb = (const float*)d_in[1];
  const float* l0_w = (const float*)d_in[11];
  const float* res_w= (const float*)d_in[13];
  const float* l1_w = (const float*)d_in[15];
  const float* l0_b = (const float*)d_in[12];
  const float* res_b= (const float*)d_in[14];
  const float* l1_b = (const float*)d_in[16];
  const int N = in_sizes[0] / 3;

  char* ws = (char*)d_ws;
  const size_t woff_l0  = 0;                          // 256*96*2
  const size_t woff_res = 49152;                      // 9*65536*2
  const size_t woff_l1  = woff_res + 9*65536*2;       // 16*256*2
  const size_t foff     = woff_l1 + 8192;             // feats: N*96*2
  const size_t poff     = foff + (size_t)N*96*2;      // f16 planes

  static const int HWs[3] = {128*128, 256*256, 512*512};
  size_t pel[9]; size_t tot = 0;
  for (int s=0;s<3;s++) for (int p=0;p<3;p++){ pel[s*3+p] = tot; tot += (size_t)HWs[s]*32; }

  const bool tr_mode = (ws_size >= poff + tot*2);

  // weights -> fragment-ordered f16
  wconv_kernel<<<(24576+255)/256,  256, 0, stream>>>(l0_w, (u16*)(ws+woff_l0), 96, 256, 24576);
  wconv_kernel<<<(589824+255)/256, 256, 0, stream>>>(res_w,(u16*)(ws+woff_res),256, 256, 589824);
  wconv_kernel<<<(4096+255)/256,   256, 0, stream>>>(l1_w, (u16*)(ws+woff_l1), 256, 16,  4096);

  PlanePtrs pp;
  if (tr_mode){
    u16* pbase = (u16*)(ws + poff);
    for (int i=0;i<9;i++){
      int s = i/3;
      ptrans_kernel<<<HWs[s]/256, 256, 0, stream>>>((const float*)d_in[2+i], pbase + pel[i], HWs[s]);
      pp.p[i] = pbase + pel[i];
    }
    interp_kernel<true><<<(N+255)/256, 256, 0, stream>>>(pts, aabb, pp, (u16*)(ws+foff), N);
  } else {
    for (int i=0;i<9;i++) pp.p[i] = d_in[2+i];
    interp_kernel<false><<<(N+255)/256, 256, 0, stream>>>(pts, aabb, pp, (u16*)(ws+foff), N);
  }

  mlp_kernel<<<N/64, 256, 0, stream>>>((const u16*)(ws+foff),
      (const u16*)(ws+woff_l0), (const u16*)(ws+woff_res), (const u16*)(ws+woff_l1),
      l0_b, res_b, l1_b, (float*)d_out);
}

// Round 5
// 433.360 us; speedup vs baseline: 2.4000x; 1.8630x over previous
//
#include <hip/hip_runtime.h>

typedef unsigned short u16;
typedef unsigned int u32;
typedef __attribute__((ext_vector_type(8))) short short8;
typedef __attribute__((ext_vector_type(8))) _Float16 half8;
typedef __attribute__((ext_vector_type(2))) _Float16 half2v;
typedef __attribute__((ext_vector_type(2))) __fp16 fp16x2;
typedef __attribute__((ext_vector_type(4))) float floatx4;

__device__ __forceinline__ u16 f2h(float f){ _Float16 h = (_Float16)f; return __builtin_bit_cast(u16, h); }
__device__ __forceinline__ u32 pkrtz(float a, float b){
  fp16x2 h = __builtin_amdgcn_cvt_pkrtz(a, b);
  return __builtin_bit_cast(u32, h);
}

// ---------------- prep: plane transpose [C=32][HW] f32 -> [HW][C] f16
__global__ void ptrans_kernel(const float* __restrict__ src, u16* __restrict__ dst, int HW){
  __shared__ float tile[32][257];
  const int t = threadIdx.x;
  const size_t hw0 = (size_t)blockIdx.x * 256;
  #pragma unroll
  for (int c = 0; c < 32; c++) tile[c][t] = src[(size_t)c*HW + hw0 + t];
  __syncthreads();
  u32* d32 = (u32*)(dst + hw0*32);
  #pragma unroll
  for (int i = 0; i < 16; i++){
    int idx = i*512 + t*2;
    int j = idx >> 5, cc = idx & 31;
    u32 lo = f2h(tile[cc][j]);
    u32 hi = f2h(tile[cc+1][j]);
    d32[i*256 + t] = lo | (hi << 16);
  }
}

// ---------------- prep: weights -> MFMA-fragment order f16
// Logical WT[n][k] = src[m][k][n]; stored as dst[m][ct][ks][lane][e]:
//   col = ct*16 + (lane&15), k = ks*32 + (lane>>4)*8 + e
// so a wave's b-fragment load for (ct,ks) is one contiguous 1KB burst.
__global__ void wconv_kernel(const float* __restrict__ src, u16* __restrict__ dst,
                             int fin, int fout, int total){
  int t = blockIdx.x*256 + threadIdx.x;
  if (t >= total) return;
  int per = fin * fout;
  int m = t / per, r = t - m*per;
  int KS = fin >> 5;
  int e = r & 7;
  int lane = (r >> 3) & 63;
  int fs = r >> 9;                 // fragment-slot: ct*KS + ks
  int ks = fs % KS, ct = fs / KS;
  int col = ct*16 + (lane & 15);
  int k   = ks*32 + (lane >> 4)*8 + e;
  dst[t] = f2h(src[(size_t)m*per + (size_t)k*fout + col]);
}

// ---------------- interpolation
struct PlanePtrs { const void* p[9]; };

__device__ __forceinline__ void load8h(const u16* p, float* f){
  half8 h = *(const half8*)p;
  #pragma unroll
  for (int e=0;e<8;e++) f[e] = (float)h[e];
}

template<bool TR>
__global__ void interp_kernel(const float* __restrict__ pts, const float* __restrict__ aabb,
                              PlanePtrs pp, u16* __restrict__ feats, int N)
{
  int n = blockIdx.x*256 + threadIdx.x;
  if (n >= N) return;
  float xn[3];
  #pragma unroll
  for (int d=0; d<3; d++){
    float lo = aabb[d], hi = aabb[3+d];
    xn[d] = (pts[(size_t)n*3 + d] - lo) * (2.0f/(hi - lo)) - 1.0f;
  }
  const int c0s[3] = {0,0,1};
  const int c1s[3] = {1,2,2};
  #pragma unroll
  for (int s=0; s<3; s++){
    const int R = 128 << s;
    float prod[32];
    #pragma unroll
    for (int p=0; p<3; p++){
      float fx = (xn[c0s[p]] + 1.0f) * 0.5f * (float)(R-1);
      float fy = (xn[c1s[p]] + 1.0f) * 0.5f * (float)(R-1);
      float fx0 = fminf(fmaxf(floorf(fx), 0.0f), (float)(R-2));
      float fy0 = fminf(fmaxf(floorf(fy), 0.0f), (float)(R-2));
      int x0 = (int)fx0, y0 = (int)fy0;
      float wx = fx - fx0, wy = fy - fy0;
      float w00 = (1.0f-wx)*(1.0f-wy), w01 = wx*(1.0f-wy);
      float w10 = (1.0f-wx)*wy,        w11 = wx*wy;
      if constexpr (TR){
        const u16* base = (const u16*)pp.p[s*3 + p];
        const u16* b00 = base + ((size_t)y0*R + x0)*32;
        const u16* b10 = b00 + (size_t)R*32;
        #pragma unroll
        for (int v=0; v<4; v++){
          float f00[8], f01[8], f10[8], f11[8];
          load8h(b00 + v*8,      f00);
          load8h(b00 + 32 + v*8, f01);
          load8h(b10 + v*8,      f10);
          load8h(b10 + 32 + v*8, f11);
          #pragma unroll
          for (int e=0; e<8; e++){
            int c = v*8 + e;
            float val = f00[e]*w00 + f01[e]*w01 + f10[e]*w10 + f11[e]*w11;
            prod[c] = (p == 0) ? val : prod[c]*val;
          }
        }
      } else {
        const size_t HW = (size_t)R*R;
        const float* b00f = (const float*)pp.p[s*3+p] + (size_t)y0*R + x0;
        #pragma unroll 4
        for (int c=0; c<32; c++){
          const float* q = b00f + (size_t)c*HW;
          float val = q[0]*w00 + q[1]*w01 + q[R]*w10 + q[R+1]*w11;
          prod[c] = (p == 0) ? val : prod[c]*val;
        }
      }
    }
    #pragma unroll
    for (int v=0; v<4; v++){
      short8 pk;
      #pragma unroll
      for (int e=0; e<8; e++) pk[e] = (short)f2h(prod[v*8+e]);
      *(short8*)(feats + (size_t)n*96 + s*32 + v*8) = pk;
    }
  }
}

// ---------------- fused MLP (fp16 MFMA)
// X in LDS: [64 rows][256 cols] f16, byte addr = (row*512 + col*2) ^ ((row&7)<<4)
// Weights in fragment order: WTs[(ct*KSTEPS + ks)*512 + lane*8 + e]
// NOTE: ks loop is deliberately NOT unrolled (unroll 1) and has no manual
// prefetch: arch-VGPR budget at 2 waves/SIMD is ~128 (compiler splits the
// unified RF ~50/50 with AGPRs); full unroll let the scheduler inflate live
// ranges past that and spill (R3/R4: 1.5 GB scratch HBM traffic).
template<int KSTEPS>
__device__ __forceinline__ void mm_tile(const u16* X, const u16* __restrict__ WTs,
                                        int ctbase, int lane, floatx4 acc[4][4])
{
  const int lr = lane & 15, lg = lane >> 4;
  #pragma unroll
  for (int rf=0; rf<4; rf++)
    #pragma unroll
    for (int cf=0; cf<4; cf++)
      acc[rf][cf] = (floatx4){0.0f, 0.0f, 0.0f, 0.0f};
  #pragma unroll 1
  for (int ks=0; ks<KSTEPS; ks++){
    half8 b[4];
    #pragma unroll
    for (int cf=0; cf<4; cf++)
      b[cf] = *(const half8*)(WTs + ((size_t)((ctbase+cf)*KSTEPS + ks)*64 + lane)*8);
    half8 a[4];
    #pragma unroll
    for (int rf=0; rf<4; rf++){
      int row = rf*16 + lr;
      int byt = (row*512 + (ks*32 + lg*8)*2) ^ ((row & 7) << 4);
      a[rf] = *(const half8*)((const char*)X + byt);
    }
    #pragma unroll
    for (int rf=0; rf<4; rf++)
      #pragma unroll
      for (int cf=0; cf<4; cf++)
        acc[rf][cf] = __builtin_amdgcn_mfma_f32_16x16x32_f16(a[rf], b[cf], acc[rf][cf], 0, 0, 0);
  }
}

__global__ __launch_bounds__(256, 2) void mlp_kernel(
    const u16* __restrict__ feats,
    const u16* __restrict__ l0T, const u16* __restrict__ resT, const u16* __restrict__ l1T,
    const float* __restrict__ l0_b, const float* __restrict__ res_b, const float* __restrict__ l1_b,
    float* __restrict__ out)
{
  __shared__ u16 X[64*256];
  const int tid = threadIdx.x;
  const int wave = tid >> 6, lane = tid & 63;
  const int lr = lane & 15, lg = lane >> 4;
  const int n0 = blockIdx.x * 64;
  const int ctbase = wave * 4;          // column-tile base (16 cols per ct)
  const int colbase = wave * 64;

  // stage feats tile: 64 rows x 96 cols f16
  #pragma unroll
  for (int i=0; i<3; i++){
    int id = tid + i*256;
    int row = id / 12, sub = id - row*12;
    short8 v = *(const short8*)(feats + (size_t)(n0+row)*96 + sub*8);
    int byt = (row*512 + sub*16) ^ ((row & 7) << 4);
    *(short8*)((char*)X + byt) = v;
  }
  __syncthreads();

  floatx4 acc[4][4];
  u32 pk[4][4][2];   // this wave's current x tile, packed f16 pairs (rows r=0,1 | r=2,3)

  // ---- L0: K=96, no activation
  mm_tile<3>(X, l0T, ctbase, lane, acc);
  __syncthreads();
  #pragma unroll
  for (int cf=0; cf<4; cf++){
    int col = colbase + cf*16 + lr;
    float bb = l0_b[col];
    #pragma unroll
    for (int rf=0; rf<4; rf++){
      float v0 = acc[rf][cf][0] + bb, v1 = acc[rf][cf][1] + bb;
      float v2 = acc[rf][cf][2] + bb, v3 = acc[rf][cf][3] + bb;
      u32 p0 = pkrtz(v0, v1), p1 = pkrtz(v2, v3);
      pk[rf][cf][0] = p0; pk[rf][cf][1] = p1;
      int row = rf*16 + lg*4;
      int b0y = ((row+0)*512 + col*2) ^ (((row+0)&7)<<4);
      int b1y = ((row+1)*512 + col*2) ^ (((row+1)&7)<<4);
      int b2y = ((row+2)*512 + col*2) ^ (((row+2)&7)<<4);
      int b3y = ((row+3)*512 + col*2) ^ (((row+3)&7)<<4);
      *(u16*)((char*)X + b0y) = (u16)p0;
      *(u16*)((char*)X + b1y) = (u16)(p0 >> 16);
      *(u16*)((char*)X + b2y) = (u16)p1;
      *(u16*)((char*)X + b3y) = (u16)(p1 >> 16);
    }
  }
  __syncthreads();

  // ---- 3 ResBlocks
  for (int rb=0; rb<3; rb++){
    const u16* W0 = resT + (size_t)(rb*3+0)*65536;
    const u16* W1 = resT + (size_t)(rb*3+1)*65536;
    const u16* W2 = resT + (size_t)(rb*3+2)*65536;
    const float* b0 = res_b + (rb*3+0)*256;
    const float* b1 = res_b + (rb*3+1)*256;
    const float* b2 = res_b + (rb*3+2)*256;

    // res = x + relu(x@W0+b0): x comes from pk (no LDS re-read)
    mm_tile<8>(X, W0, ctbase, lane, acc);
    __syncthreads();
    #pragma unroll
    for (int cf=0; cf<4; cf++){
      int col = colbase + cf*16 + lr;
      float bb = b0[col];
      #pragma unroll
      for (int rf=0; rf<4; rf++){
        half2v x01 = __builtin_bit_cast(half2v, pk[rf][cf][0]);
        half2v x23 = __builtin_bit_cast(half2v, pk[rf][cf][1]);
        float v0 = (float)x01[0] + fmaxf(acc[rf][cf][0] + bb, 0.0f);
        float v1 = (float)x01[1] + fmaxf(acc[rf][cf][1] + bb, 0.0f);
        float v2 = (float)x23[0] + fmaxf(acc[rf][cf][2] + bb, 0.0f);
        float v3 = (float)x23[1] + fmaxf(acc[rf][cf][3] + bb, 0.0f);
        u32 p0 = pkrtz(v0, v1), p1 = pkrtz(v2, v3);
        pk[rf][cf][0] = p0; pk[rf][cf][1] = p1;   // pk now holds res
        int row = rf*16 + lg*4;
        int b0y = ((row+0)*512 + col*2) ^ (((row+0)&7)<<4);
        int b1y = ((row+1)*512 + col*2) ^ (((row+1)&7)<<4);
        int b2y = ((row+2)*512 + col*2) ^ (((row+2)&7)<<4);
        int b3y = ((row+3)*512 + col*2) ^ (((row+3)&7)<<4);
        *(u16*)((char*)X + b0y) = (u16)p0;
        *(u16*)((char*)X + b1y) = (u16)(p0 >> 16);
        *(u16*)((char*)X + b2y) = (u16)p1;
        *(u16*)((char*)X + b3y) = (u16)(p1 >> 16);
      }
    }
    __syncthreads();

    // x = relu(res@W1+b1) -> X only
    mm_tile<8>(X, W1, ctbase, lane, acc);
    __syncthreads();
    #pragma unroll
    for (int cf=0; cf<4; cf++){
      int col = colbase + cf*16 + lr;
      float bb = b1[col];
      #pragma unroll
      for (int rf=0; rf<4; rf++){
        float v0 = fmaxf(acc[rf][cf][0] + bb, 0.0f), v1 = fmaxf(acc[rf][cf][1] + bb, 0.0f);
        float v2 = fmaxf(acc[rf][cf][2] + bb, 0.0f), v3 = fmaxf(acc[rf][cf][3] + bb, 0.0f);
        u32 p0 = pkrtz(v0, v1), p1 = pkrtz(v2, v3);
        int row = rf*16 + lg*4;
        int b0y = ((row+0)*512 + col*2) ^ (((row+0)&7)<<4);
        int b1y = ((row+1)*512 + col*2) ^ (((row+1)&7)<<4);
        int b2y = ((row+2)*512 + col*2) ^ (((row+2)&7)<<4);
        int b3y = ((row+3)*512 + col*2) ^ (((row+3)&7)<<4);
        *(u16*)((char*)X + b0y) = (u16)p0;
        *(u16*)((char*)X + b1y) = (u16)(p0 >> 16);
        *(u16*)((char*)X + b2y) = (u16)p1;
        *(u16*)((char*)X + b3y) = (u16)(p1 >> 16);
      }
    }
    __syncthreads();

    // x = relu(x@W2+b2) + res(pk)
    mm_tile<8>(X, W2, ctbase, lane, acc);
    __syncthreads();
    #pragma unroll
    for (int cf=0; cf<4; cf++){
      int col = colbase + cf*16 + lr;
      float bb = b2[col];
      #pragma unroll
      for (int rf=0; rf<4; rf++){
        half2v r01 = __builtin_bit_cast(half2v, pk[rf][cf][0]);
        half2v r23 = __builtin_bit_cast(half2v, pk[rf][cf][1]);
        float v0 = fmaxf(acc[rf][cf][0] + bb, 0.0f) + (float)r01[0];
        float v1 = fmaxf(acc[rf][cf][1] + bb, 0.0f) + (float)r01[1];
        float v2 = fmaxf(acc[rf][cf][2] + bb, 0.0f) + (float)r23[0];
        float v3 = fmaxf(acc[rf][cf][3] + bb, 0.0f) + (float)r23[1];
        u32 p0 = pkrtz(v0, v1), p1 = pkrtz(v2, v3);
        pk[rf][cf][0] = p0; pk[rf][cf][1] = p1;   // pk now holds new x
        int row = rf*16 + lg*4;
        int b0y = ((row+0)*512 + col*2) ^ (((row+0)&7)<<4);
        int b1y = ((row+1)*512 + col*2) ^ (((row+1)&7)<<4);
        int b2y = ((row+2)*512 + col*2) ^ (((row+2)&7)<<4);
        int b3y = ((row+3)*512 + col*2) ^ (((row+3)&7)<<4);
        *(u16*)((char*)X + b0y) = (u16)p0;
        *(u16*)((char*)X + b1y) = (u16)(p0 >> 16);
        *(u16*)((char*)X + b2y) = (u16)p1;
        *(u16*)((char*)X + b3y) = (u16)(p1 >> 16);
      }
    }
    __syncthreads();
  }

  // ---- final: 256 -> 16, sigmoid. Each wave: 16 rows x 16 cols.
  floatx4 accf = {0.0f, 0.0f, 0.0f, 0.0f};
  #pragma unroll 1
  for (int ks=0; ks<8; ks++){
    int row = wave*16 + lr;
    int byt = (row*512 + (ks*32 + lg*8)*2) ^ ((row&7)<<4);
    half8 a = *(const half8*)((const char*)X + byt);
    half8 b = *(const half8*)(l1T + ((size_t)ks*64 + lane)*8);
    accf = __builtin_amdgcn_mfma_f32_16x16x32_f16(a, b, accf, 0, 0, 0);
  }
  float bo = l1_b[lr];
  #pragma unroll
  for (int r=0; r<4; r++){
    int row = wave*16 + lg*4 + r;
    float v = accf[r] + bo;
    v = 1.0f / (1.0f + __expf(-v));
    out[(size_t)(n0+row)*16 + lr] = v;
  }
}

// ---------------- host
extern "C" void kernel_launch(void* const* d_in, const int* in_sizes, int n_in,
                              void* d_out, int out_size, void* d_ws, size_t ws_size,
                              hipStream_t stream)
{
  const float* pts  = (const float*)d_in[0];
  const float* aabb = (const float*)d_in[1];
  const float* l0_w = (const float*)d_in[11];
  const float* res_w= (const float*)d_in[13];
  const float* l1_w = (const float*)d_in[15];
  const float* l0_b = (const float*)d_in[12];
  const float* res_b= (const float*)d_in[14];
  const float* l1_b = (const float*)d_in[16];
  const int N = in_sizes[0] / 3;

  char* ws = (char*)d_ws;
  const size_t woff_l0  = 0;                          // 256*96*2
  const size_t woff_res = 49152;                      // 9*65536*2
  const size_t woff_l1  = woff_res + 9*65536*2;       // 16*256*2
  const size_t foff     = woff_l1 + 8192;             // feats: N*96*2
  const size_t poff     = foff + (size_t)N*96*2;      // f16 planes

  static const int HWs[3] = {128*128, 256*256, 512*512};
  size_t pel[9]; size_t tot = 0;
  for (int s=0;s<3;s++) for (int p=0;p<3;p++){ pel[s*3+p] = tot; tot += (size_t)HWs[s]*32; }

  const bool tr_mode = (ws_size >= poff + tot*2);

  // weights -> fragment-ordered f16
  wconv_kernel<<<(24576+255)/256,  256, 0, stream>>>(l0_w, (u16*)(ws+woff_l0), 96, 256, 24576);
  wconv_kernel<<<(589824+255)/256, 256, 0, stream>>>(res_w,(u16*)(ws+woff_res),256, 256, 589824);
  wconv_kernel<<<(4096+255)/256,   256, 0, stream>>>(l1_w, (u16*)(ws+woff_l1), 256, 16,  4096);

  PlanePtrs pp;
  if (tr_mode){
    u16* pbase = (u16*)(ws + poff);
    for (int i=0;i<9;i++){
      int s = i/3;
      ptrans_kernel<<<HWs[s]/256, 256, 0, stream>>>((const float*)d_in[2+i], pbase + pel[i], HWs[s]);
      pp.p[i] = pbase + pel[i];
    }
    interp_kernel<true><<<(N+255)/256, 256, 0, stream>>>(pts, aabb, pp, (u16*)(ws+foff), N);
  } else {
    for (int i=0;i<9;i++) pp.p[i] = d_in[2+i];
    interp_kernel<false><<<(N+255)/256, 256, 0, stream>>>(pts, aabb, pp, (u16*)(ws+foff), N);
  }

  mlp_kernel<<<N/64, 256, 0, stream>>>((const u16*)(ws+foff),
      (const u16*)(ws+woff_l0), (const u16*)(ws+woff_res), (const u16*)(ws+woff_l1),
      l0_b, res_b, l1_b, (float*)d_out);
}

// Round 6
// 289.527 us; speedup vs baseline: 3.5923x; 1.4968x over previous
//
#include <hip/hip_runtime.h>

typedef unsigned short u16;
typedef unsigned int u32;
typedef __attribute__((ext_vector_type(8))) short short8;
typedef __attribute__((ext_vector_type(8))) _Float16 half8;
typedef __attribute__((ext_vector_type(2))) _Float16 half2v;
typedef __attribute__((ext_vector_type(2))) __fp16 fp16x2;
typedef __attribute__((ext_vector_type(4))) float floatx4;

__device__ __forceinline__ u16 f2h(float f){ _Float16 h = (_Float16)f; return __builtin_bit_cast(u16, h); }
__device__ __forceinline__ u32 pkrtz(float a, float b){
  fp16x2 h = __builtin_amdgcn_cvt_pkrtz(a, b);
  return __builtin_bit_cast(u32, h);
}

// ---------------- prep: plane transpose [C=32][HW] f32 -> [HW][C] f16
__global__ void ptrans_kernel(const float* __restrict__ src, u16* __restrict__ dst, int HW){
  __shared__ float tile[32][257];
  const int t = threadIdx.x;
  const size_t hw0 = (size_t)blockIdx.x * 256;
  #pragma unroll
  for (int c = 0; c < 32; c++) tile[c][t] = src[(size_t)c*HW + hw0 + t];
  __syncthreads();
  u32* d32 = (u32*)(dst + hw0*32);
  #pragma unroll
  for (int i = 0; i < 16; i++){
    int idx = i*512 + t*2;
    int j = idx >> 5, cc = idx & 31;
    u32 lo = f2h(tile[cc][j]);
    u32 hi = f2h(tile[cc+1][j]);
    d32[i*256 + t] = lo | (hi << 16);
  }
}

// ---------------- prep: weights -> MFMA-fragment order f16
// Logical WT[n][k] = src[m][k][n]; stored as dst[m][ct][ks][lane][e]:
//   col = ct*16 + (lane&15), k = ks*32 + (lane>>4)*8 + e
__global__ void wconv_kernel(const float* __restrict__ src, u16* __restrict__ dst,
                             int fin, int fout, int total){
  int t = blockIdx.x*256 + threadIdx.x;
  if (t >= total) return;
  int per = fin * fout;
  int m = t / per, r = t - m*per;
  int KS = fin >> 5;
  int e = r & 7;
  int lane = (r >> 3) & 63;
  int fs = r >> 9;                 // fragment-slot: ct*KS + ks
  int ks = fs % KS, ct = fs / KS;
  int col = ct*16 + (lane & 15);
  int k   = ks*32 + (lane >> 4)*8 + e;
  dst[t] = f2h(src[(size_t)m*per + (size_t)k*fout + col]);
}

// ---------------- interpolation
struct PlanePtrs { const void* p[9]; };

// 4 threads per point; thread (n, v) handles channels v*8..v*8+7.
// Light per-thread state (prod[8], 36x16B loads) -> 4x wave count vs 1-thread/pt,
// hides scattered-L2 gather latency. 4-lane groups read contiguous 64B.
__global__ void interp4_kernel(const float* __restrict__ pts, const float* __restrict__ aabb,
                               PlanePtrs pp, u16* __restrict__ feats, int N)
{
  int g = blockIdx.x*256 + threadIdx.x;
  int n = g >> 2, v = g & 3;
  if (n >= N) return;
  float xn[3];
  #pragma unroll
  for (int d=0; d<3; d++){
    float lo = aabb[d], hi = aabb[3+d];
    xn[d] = (pts[(size_t)n*3 + d] - lo) * (2.0f/(hi - lo)) - 1.0f;
  }
  const int c0s[3] = {0,0,1};
  const int c1s[3] = {1,2,2};
  #pragma unroll
  for (int s=0; s<3; s++){
    const int R = 128 << s;
    float prod[8];
    #pragma unroll
    for (int p=0; p<3; p++){
      float fx = (xn[c0s[p]] + 1.0f) * 0.5f * (float)(R-1);
      float fy = (xn[c1s[p]] + 1.0f) * 0.5f * (float)(R-1);
      float fx0 = fminf(fmaxf(floorf(fx), 0.0f), (float)(R-2));
      float fy0 = fminf(fmaxf(floorf(fy), 0.0f), (float)(R-2));
      int x0 = (int)fx0, y0 = (int)fy0;
      float wx = fx - fx0, wy = fy - fy0;
      float w00 = (1.0f-wx)*(1.0f-wy), w01 = wx*(1.0f-wy);
      float w10 = (1.0f-wx)*wy,        w11 = wx*wy;
      const u16* base = (const u16*)pp.p[s*3 + p];
      const u16* b00 = base + ((size_t)y0*R + x0)*32 + v*8;
      const u16* b10 = b00 + (size_t)R*32;
      half8 h00 = *(const half8*)b00;
      half8 h01 = *(const half8*)(b00 + 32);
      half8 h10 = *(const half8*)b10;
      half8 h11 = *(const half8*)(b10 + 32);
      #pragma unroll
      for (int e=0; e<8; e++){
        float val = (float)h00[e]*w00 + (float)h01[e]*w01 + (float)h10[e]*w10 + (float)h11[e]*w11;
        prod[e] = (p == 0) ? val : prod[e]*val;
      }
    }
    short8 pk8;
    #pragma unroll
    for (int e=0; e<8; e++) pk8[e] = (short)f2h(prod[e]);
    *(short8*)(feats + (size_t)n*96 + s*32 + v*8) = pk8;
  }
}

// fallback: original 1-thread/point gather from untransposed planes
__global__ void interp_fb_kernel(const float* __restrict__ pts, const float* __restrict__ aabb,
                                 PlanePtrs pp, u16* __restrict__ feats, int N)
{
  int n = blockIdx.x*256 + threadIdx.x;
  if (n >= N) return;
  float xn[3];
  #pragma unroll
  for (int d=0; d<3; d++){
    float lo = aabb[d], hi = aabb[3+d];
    xn[d] = (pts[(size_t)n*3 + d] - lo) * (2.0f/(hi - lo)) - 1.0f;
  }
  const int c0s[3] = {0,0,1};
  const int c1s[3] = {1,2,2};
  #pragma unroll
  for (int s=0; s<3; s++){
    const int R = 128 << s;
    float prod[32];
    #pragma unroll
    for (int p=0; p<3; p++){
      float fx = (xn[c0s[p]] + 1.0f) * 0.5f * (float)(R-1);
      float fy = (xn[c1s[p]] + 1.0f) * 0.5f * (float)(R-1);
      float fx0 = fminf(fmaxf(floorf(fx), 0.0f), (float)(R-2));
      float fy0 = fminf(fmaxf(floorf(fy), 0.0f), (float)(R-2));
      int x0 = (int)fx0, y0 = (int)fy0;
      float wx = fx - fx0, wy = fy - fy0;
      float w00 = (1.0f-wx)*(1.0f-wy), w01 = wx*(1.0f-wy);
      float w10 = (1.0f-wx)*wy,        w11 = wx*wy;
      const size_t HW = (size_t)R*R;
      const float* b00f = (const float*)pp.p[s*3+p] + (size_t)y0*R + x0;
      #pragma unroll 4
      for (int c=0; c<32; c++){
        const float* q = b00f + (size_t)c*HW;
        float val = q[0]*w00 + q[1]*w01 + q[R]*w10 + q[R+1]*w11;
        prod[c] = (p == 0) ? val : prod[c]*val;
      }
    }
    #pragma unroll
    for (int vv=0; vv<4; vv++){
      short8 pk8;
      #pragma unroll
      for (int e=0; e<8; e++) pk8[e] = (short)f2h(prod[vv*8+e]);
      *(short8*)(feats + (size_t)n*96 + s*32 + vv*8) = pk8;
    }
  }
}

// ---------------- fused MLP (fp16 MFMA)
// X (double-buffered): [64 rows][256 cols] f16, byte addr = (row*512 + col*2) ^ ((row&7)<<4)
// Weights in fragment order: WTs[(ct*KSTEPS + ks)*512 + lane*8 + e]
// ks loop NOT unrolled, no manual prefetch: arch-VGPR budget at 2 waves/SIMD
// is ~128 (unified RF split with AGPRs); unrolling spilled in R3/R4.
template<int KSTEPS>
__device__ __forceinline__ void mm_tile(const u16* X, const u16* __restrict__ WTs,
                                        int ctbase, int lane, floatx4 acc[4][4])
{
  const int lr = lane & 15, lg = lane >> 4;
  #pragma unroll
  for (int rf=0; rf<4; rf++)
    #pragma unroll
    for (int cf=0; cf<4; cf++)
      acc[rf][cf] = (floatx4){0.0f, 0.0f, 0.0f, 0.0f};
  #pragma unroll 1
  for (int ks=0; ks<KSTEPS; ks++){
    half8 b[4];
    #pragma unroll
    for (int cf=0; cf<4; cf++)
      b[cf] = *(const half8*)(WTs + ((size_t)((ctbase+cf)*KSTEPS + ks)*64 + lane)*8);
    half8 a[4];
    #pragma unroll
    for (int rf=0; rf<4; rf++){
      int row = rf*16 + lr;
      int byt = (row*512 + (ks*32 + lg*8)*2) ^ ((row & 7) << 4);
      a[rf] = *(const half8*)((const char*)X + byt);
    }
    __builtin_amdgcn_s_setprio(1);
    #pragma unroll
    for (int rf=0; rf<4; rf++)
      #pragma unroll
      for (int cf=0; cf<4; cf++)
        acc[rf][cf] = __builtin_amdgcn_mfma_f32_16x16x32_f16(a[rf], b[cf], acc[rf][cf], 0, 0, 0);
    __builtin_amdgcn_s_setprio(0);
  }
}

__global__ __launch_bounds__(256, 2) void mlp_kernel(
    const u16* __restrict__ feats,
    const u16* __restrict__ l0T, const u16* __restrict__ resT, const u16* __restrict__ l1T,
    const float* __restrict__ l0_b, const float* __restrict__ res_b, const float* __restrict__ l1_b,
    float* __restrict__ out)
{
  __shared__ u16 Xb[2][64*256];
  const int tid = threadIdx.x;
  const int wave = tid >> 6, lane = tid & 63;
  const int lr = lane & 15, lg = lane >> 4;
  const int n0 = blockIdx.x * 64;
  const int ctbase = wave * 4;          // column-tile base (16 cols per ct)
  const int colbase = wave * 64;

  // stage feats tile into buf0: 64 rows x 96 cols f16
  #pragma unroll
  for (int i=0; i<3; i++){
    int id = tid + i*256;
    int row = id / 12, sub = id - row*12;
    short8 v = *(const short8*)(feats + (size_t)(n0+row)*96 + sub*8);
    int byt = (row*512 + sub*16) ^ ((row & 7) << 4);
    *(short8*)((char*)Xb[0] + byt) = v;
  }
  __syncthreads();

  floatx4 acc[4][4];
  u32 pk[4][4][2];   // this wave's current x tile, packed f16 pairs (rows r=0,1 | r=2,3)
  int cur = 0;       // buffer holding current activations

  // ---- L0: K=96, no activation.  read buf0 -> write buf1
  mm_tile<3>(Xb[0], l0T, ctbase, lane, acc);
  {
    char* Xw = (char*)Xb[1];
    #pragma unroll
    for (int cf=0; cf<4; cf++){
      int col = colbase + cf*16 + lr;
      float bb = l0_b[col];
      #pragma unroll
      for (int rf=0; rf<4; rf++){
        float v0 = acc[rf][cf][0] + bb, v1 = acc[rf][cf][1] + bb;
        float v2 = acc[rf][cf][2] + bb, v3 = acc[rf][cf][3] + bb;
        u32 p0 = pkrtz(v0, v1), p1 = pkrtz(v2, v3);
        pk[rf][cf][0] = p0; pk[rf][cf][1] = p1;
        int row = rf*16 + lg*4;
        int b0y = ((row+0)*512 + col*2) ^ (((row+0)&7)<<4);
        int b1y = ((row+1)*512 + col*2) ^ (((row+1)&7)<<4);
        int b2y = ((row+2)*512 + col*2) ^ (((row+2)&7)<<4);
        int b3y = ((row+3)*512 + col*2) ^ (((row+3)&7)<<4);
        *(u16*)(Xw + b0y) = (u16)p0;
        *(u16*)(Xw + b1y) = (u16)(p0 >> 16);
        *(u16*)(Xw + b2y) = (u16)p1;
        *(u16*)(Xw + b3y) = (u16)(p1 >> 16);
      }
    }
  }
  __syncthreads();
  cur = 1;

  // ---- 3 ResBlocks; each layer: read Xb[cur] -> write Xb[cur^1], 1 barrier
  for (int rb=0; rb<3; rb++){
    const u16* W0 = resT + (size_t)(rb*3+0)*65536;
    const u16* W1 = resT + (size_t)(rb*3+1)*65536;
    const u16* W2 = resT + (size_t)(rb*3+2)*65536;
    const float* b0 = res_b + (rb*3+0)*256;
    const float* b1 = res_b + (rb*3+1)*256;
    const float* b2 = res_b + (rb*3+2)*256;

    // res = x + relu(x@W0+b0): x comes from pk (no LDS re-read)
    mm_tile<8>(Xb[cur], W0, ctbase, lane, acc);
    {
      char* Xw = (char*)Xb[cur^1];
      #pragma unroll
      for (int cf=0; cf<4; cf++){
        int col = colbase + cf*16 + lr;
        float bb = b0[col];
        #pragma unroll
        for (int rf=0; rf<4; rf++){
          half2v x01 = __builtin_bit_cast(half2v, pk[rf][cf][0]);
          half2v x23 = __builtin_bit_cast(half2v, pk[rf][cf][1]);
          float v0 = (float)x01[0] + fmaxf(acc[rf][cf][0] + bb, 0.0f);
          float v1 = (float)x01[1] + fmaxf(acc[rf][cf][1] + bb, 0.0f);
          float v2 = (float)x23[0] + fmaxf(acc[rf][cf][2] + bb, 0.0f);
          float v3 = (float)x23[1] + fmaxf(acc[rf][cf][3] + bb, 0.0f);
          u32 p0 = pkrtz(v0, v1), p1 = pkrtz(v2, v3);
          pk[rf][cf][0] = p0; pk[rf][cf][1] = p1;   // pk now holds res
          int row = rf*16 + lg*4;
          int b0y = ((row+0)*512 + col*2) ^ (((row+0)&7)<<4);
          int b1y = ((row+1)*512 + col*2) ^ (((row+1)&7)<<4);
          int b2y = ((row+2)*512 + col*2) ^ (((row+2)&7)<<4);
          int b3y = ((row+3)*512 + col*2) ^ (((row+3)&7)<<4);
          *(u16*)(Xw + b0y) = (u16)p0;
          *(u16*)(Xw + b1y) = (u16)(p0 >> 16);
          *(u16*)(Xw + b2y) = (u16)p1;
          *(u16*)(Xw + b3y) = (u16)(p1 >> 16);
        }
      }
    }
    __syncthreads();
    cur ^= 1;

    // x = relu(res@W1+b1) -> LDS only
    mm_tile<8>(Xb[cur], W1, ctbase, lane, acc);
    {
      char* Xw = (char*)Xb[cur^1];
      #pragma unroll
      for (int cf=0; cf<4; cf++){
        int col = colbase + cf*16 + lr;
        float bb = b1[col];
        #pragma unroll
        for (int rf=0; rf<4; rf++){
          float v0 = fmaxf(acc[rf][cf][0] + bb, 0.0f), v1 = fmaxf(acc[rf][cf][1] + bb, 0.0f);
          float v2 = fmaxf(acc[rf][cf][2] + bb, 0.0f), v3 = fmaxf(acc[rf][cf][3] + bb, 0.0f);
          u32 p0 = pkrtz(v0, v1), p1 = pkrtz(v2, v3);
          int row = rf*16 + lg*4;
          int b0y = ((row+0)*512 + col*2) ^ (((row+0)&7)<<4);
          int b1y = ((row+1)*512 + col*2) ^ (((row+1)&7)<<4);
          int b2y = ((row+2)*512 + col*2) ^ (((row+2)&7)<<4);
          int b3y = ((row+3)*512 + col*2) ^ (((row+3)&7)<<4);
          *(u16*)(Xw + b0y) = (u16)p0;
          *(u16*)(Xw + b1y) = (u16)(p0 >> 16);
          *(u16*)(Xw + b2y) = (u16)p1;
          *(u16*)(Xw + b3y) = (u16)(p1 >> 16);
        }
      }
    }
    __syncthreads();
    cur ^= 1;

    // x = relu(x@W2+b2) + res(pk)
    mm_tile<8>(Xb[cur], W2, ctbase, lane, acc);
    {
      char* Xw = (char*)Xb[cur^1];
      #pragma unroll
      for (int cf=0; cf<4; cf++){
        int col = colbase + cf*16 + lr;
        float bb = b2[col];
        #pragma unroll
        for (int rf=0; rf<4; rf++){
          half2v r01 = __builtin_bit_cast(half2v, pk[rf][cf][0]);
          half2v r23 = __builtin_bit_cast(half2v, pk[rf][cf][1]);
          float v0 = fmaxf(acc[rf][cf][0] + bb, 0.0f) + (float)r01[0];
          float v1 = fmaxf(acc[rf][cf][1] + bb, 0.0f) + (float)r01[1];
          float v2 = fmaxf(acc[rf][cf][2] + bb, 0.0f) + (float)r23[0];
          float v3 = fmaxf(acc[rf][cf][3] + bb, 0.0f) + (float)r23[1];
          u32 p0 = pkrtz(v0, v1), p1 = pkrtz(v2, v3);
          pk[rf][cf][0] = p0; pk[rf][cf][1] = p1;   // pk now holds new x
          int row = rf*16 + lg*4;
          int b0y = ((row+0)*512 + col*2) ^ (((row+0)&7)<<4);
          int b1y = ((row+1)*512 + col*2) ^ (((row+1)&7)<<4);
          int b2y = ((row+2)*512 + col*2) ^ (((row+2)&7)<<4);
          int b3y = ((row+3)*512 + col*2) ^ (((row+3)&7)<<4);
          *(u16*)(Xw + b0y) = (u16)p0;
          *(u16*)(Xw + b1y) = (u16)(p0 >> 16);
          *(u16*)(Xw + b2y) = (u16)p1;
          *(u16*)(Xw + b3y) = (u16)(p1 >> 16);
        }
      }
    }
    __syncthreads();
    cur ^= 1;
  }

  // ---- final: 256 -> 16, sigmoid. Each wave: 16 rows x 16 cols.
  floatx4 accf = {0.0f, 0.0f, 0.0f, 0.0f};
  const char* Xr = (const char*)Xb[cur];
  #pragma unroll 1
  for (int ks=0; ks<8; ks++){
    int row = wave*16 + lr;
    int byt = (row*512 + (ks*32 + lg*8)*2) ^ ((row&7)<<4);
    half8 a = *(const half8*)(Xr + byt);
    half8 b = *(const half8*)(l1T + ((size_t)ks*64 + lane)*8);
    accf = __builtin_amdgcn_mfma_f32_16x16x32_f16(a, b, accf, 0, 0, 0);
  }
  float bo = l1_b[lr];
  #pragma unroll
  for (int r=0; r<4; r++){
    int row = wave*16 + lg*4 + r;
    float v = accf[r] + bo;
    v = 1.0f / (1.0f + __expf(-v));
    out[(size_t)(n0+row)*16 + lr] = v;
  }
}

// ---------------- host
extern "C" void kernel_launch(void* const* d_in, const int* in_sizes, int n_in,
                              void* d_out, int out_size, void* d_ws, size_t ws_size,
                              hipStream_t stream)
{
  const float* pts  = (const float*)d_in[0];
  const float* aabb = (const float*)d_in[1];
  const float* l0_w = (const float*)d_in[11];
  const float* res_w= (const float*)d_in[13];
  const float* l1_w = (const float*)d_in[15];
  const float* l0_b = (const float*)d_in[12];
  const float* res_b= (const float*)d_in[14];
  const float* l1_b = (const float*)d_in[16];
  const int N = in_sizes[0] / 3;

  char* ws = (char*)d_ws;
  const size_t woff_l0  = 0;                          // 256*96*2
  const size_t woff_res = 49152;                      // 9*65536*2
  const size_t woff_l1  = woff_res + 9*65536*2;       // 16*256*2
  const size_t foff     = woff_l1 + 8192;             // feats: N*96*2
  const size_t poff     = foff + (size_t)N*96*2;      // f16 planes

  static const int HWs[3] = {128*128, 256*256, 512*512};
  size_t pel[9]; size_t tot = 0;
  for (int s=0;s<3;s++) for (int p=0;p<3;p++){ pel[s*3+p] = tot; tot += (size_t)HWs[s]*32; }

  const bool tr_mode = (ws_size >= poff + tot*2);

  // weights -> fragment-ordered f16
  wconv_kernel<<<(24576+255)/256,  256, 0, stream>>>(l0_w, (u16*)(ws+woff_l0), 96, 256, 24576);
  wconv_kernel<<<(589824+255)/256, 256, 0, stream>>>(res_w,(u16*)(ws+woff_res),256, 256, 589824);
  wconv_kernel<<<(4096+255)/256,   256, 0, stream>>>(l1_w, (u16*)(ws+woff_l1), 256, 16,  4096);

  PlanePtrs pp;
  if (tr_mode){
    u16* pbase = (u16*)(ws + poff);
    for (int i=0;i<9;i++){
      int s = i/3;
      ptrans_kernel<<<HWs[s]/256, 256, 0, stream>>>((const float*)d_in[2+i], pbase + pel[i], HWs[s]);
      pp.p[i] = pbase + pel[i];
    }
    interp4_kernel<<<(4*N+255)/256, 256, 0, stream>>>(pts, aabb, pp, (u16*)(ws+foff), N);
  } else {
    for (int i=0;i<9;i++) pp.p[i] = d_in[2+i];
    interp_fb_kernel<<<(N+255)/256, 256, 0, stream>>>(pts, aabb, pp, (u16*)(ws+foff), N);
  }

  mlp_kernel<<<N/64, 256, 0, stream>>>((const u16*)(ws+foff),
      (const u16*)(ws+woff_l0), (const u16*)(ws+woff_res), (const u16*)(ws+woff_l1),
      l0_b, res_b, l1_b, (float*)d_out);
}

// Round 7
// 280.860 us; speedup vs baseline: 3.7032x; 1.0309x over previous
//
#include <hip/hip_runtime.h>

typedef unsigned short u16;
typedef unsigned int u32;
typedef __attribute__((ext_vector_type(2))) unsigned int u32x2;
typedef __attribute__((ext_vector_type(8))) short short8;
typedef __attribute__((ext_vector_type(8))) _Float16 half8;
typedef __attribute__((ext_vector_type(2))) _Float16 half2v;
typedef __attribute__((ext_vector_type(2))) __fp16 fp16x2;
typedef __attribute__((ext_vector_type(4))) float floatx4;

__device__ __forceinline__ u16 f2h(float f){ _Float16 h = (_Float16)f; return __builtin_bit_cast(u16, h); }
__device__ __forceinline__ u32 pkrtz(float a, float b){
  fp16x2 h = __builtin_amdgcn_cvt_pkrtz(a, b);
  return __builtin_bit_cast(u32, h);
}

// ---------------- prep: plane transpose [C=32][HW] f32 -> [HW][C] f16
__global__ void ptrans_kernel(const float* __restrict__ src, u16* __restrict__ dst, int HW){
  __shared__ float tile[32][257];
  const int t = threadIdx.x;
  const size_t hw0 = (size_t)blockIdx.x * 256;
  #pragma unroll
  for (int c = 0; c < 32; c++) tile[c][t] = src[(size_t)c*HW + hw0 + t];
  __syncthreads();
  u32* d32 = (u32*)(dst + hw0*32);
  #pragma unroll
  for (int i = 0; i < 16; i++){
    int idx = i*512 + t*2;
    int j = idx >> 5, cc = idx & 31;
    u32 lo = f2h(tile[cc][j]);
    u32 hi = f2h(tile[cc+1][j]);
    d32[i*256 + t] = lo | (hi << 16);
  }
}

// ---------------- prep: weights -> MFMA A-fragment order f16
// Logical A[of][k] = src[m][k][of]; stored dst[m][ft][ks][lane][e]:
//   of = ft*16 + (lane&15), k = ks*32 + (lane>>4)*8 + e
// so a wave's A-fragment load for (ft,ks) is one contiguous 1KB burst.
__global__ void wconv_kernel(const float* __restrict__ src, u16* __restrict__ dst,
                             int fin, int fout, int total){
  int t = blockIdx.x*256 + threadIdx.x;
  if (t >= total) return;
  int per = fin * fout;
  int m = t / per, r = t - m*per;
  int KS = fin >> 5;
  int e = r & 7;
  int lane = (r >> 3) & 63;
  int fs = r >> 9;                 // fragment-slot: ft*KS + ks
  int ks = fs % KS, ft = fs / KS;
  int of = ft*16 + (lane & 15);
  int k  = ks*32 + (lane >> 4)*8 + e;
  dst[t] = f2h(src[(size_t)m*per + (size_t)k*fout + of]);
}

// ---------------- interpolation
struct PlanePtrs { const void* p[9]; };

// 4 threads per point; thread (n, v) handles channels v*8..v*8+7.
__global__ void interp4_kernel(const float* __restrict__ pts, const float* __restrict__ aabb,
                               PlanePtrs pp, u16* __restrict__ feats, int N)
{
  int g = blockIdx.x*256 + threadIdx.x;
  int n = g >> 2, v = g & 3;
  if (n >= N) return;
  float xn[3];
  #pragma unroll
  for (int d=0; d<3; d++){
    float lo = aabb[d], hi = aabb[3+d];
    xn[d] = (pts[(size_t)n*3 + d] - lo) * (2.0f/(hi - lo)) - 1.0f;
  }
  const int c0s[3] = {0,0,1};
  const int c1s[3] = {1,2,2};
  #pragma unroll
  for (int s=0; s<3; s++){
    const int R = 128 << s;
    float prod[8];
    #pragma unroll
    for (int p=0; p<3; p++){
      float fx = (xn[c0s[p]] + 1.0f) * 0.5f * (float)(R-1);
      float fy = (xn[c1s[p]] + 1.0f) * 0.5f * (float)(R-1);
      float fx0 = fminf(fmaxf(floorf(fx), 0.0f), (float)(R-2));
      float fy0 = fminf(fmaxf(floorf(fy), 0.0f), (float)(R-2));
      int x0 = (int)fx0, y0 = (int)fy0;
      float wx = fx - fx0, wy = fy - fy0;
      float w00 = (1.0f-wx)*(1.0f-wy), w01 = wx*(1.0f-wy);
      float w10 = (1.0f-wx)*wy,        w11 = wx*wy;
      const u16* base = (const u16*)pp.p[s*3 + p];
      const u16* b00 = base + ((size_t)y0*R + x0)*32 + v*8;
      const u16* b10 = b00 + (size_t)R*32;
      half8 h00 = *(const half8*)b00;
      half8 h01 = *(const half8*)(b00 + 32);
      half8 h10 = *(const half8*)b10;
      half8 h11 = *(const half8*)(b10 + 32);
      #pragma unroll
      for (int e=0; e<8; e++){
        float val = (float)h00[e]*w00 + (float)h01[e]*w01 + (float)h10[e]*w10 + (float)h11[e]*w11;
        prod[e] = (p == 0) ? val : prod[e]*val;
      }
    }
    short8 pk8;
    #pragma unroll
    for (int e=0; e<8; e++) pk8[e] = (short)f2h(prod[e]);
    *(short8*)(feats + (size_t)n*96 + s*32 + v*8) = pk8;
  }
}

// fallback: 1-thread/point gather from untransposed planes
__global__ void interp_fb_kernel(const float* __restrict__ pts, const float* __restrict__ aabb,
                                 PlanePtrs pp, u16* __restrict__ feats, int N)
{
  int n = blockIdx.x*256 + threadIdx.x;
  if (n >= N) return;
  float xn[3];
  #pragma unroll
  for (int d=0; d<3; d++){
    float lo = aabb[d], hi = aabb[3+d];
    xn[d] = (pts[(size_t)n*3 + d] - lo) * (2.0f/(hi - lo)) - 1.0f;
  }
  const int c0s[3] = {0,0,1};
  const int c1s[3] = {1,2,2};
  #pragma unroll
  for (int s=0; s<3; s++){
    const int R = 128 << s;
    float prod[32];
    #pragma unroll
    for (int p=0; p<3; p++){
      float fx = (xn[c0s[p]] + 1.0f) * 0.5f * (float)(R-1);
      float fy = (xn[c1s[p]] + 1.0f) * 0.5f * (float)(R-1);
      float fx0 = fminf(fmaxf(floorf(fx), 0.0f), (float)(R-2));
      float fy0 = fminf(fmaxf(floorf(fy), 0.0f), (float)(R-2));
      int x0 = (int)fx0, y0 = (int)fy0;
      float wx = fx - fx0, wy = fy - fy0;
      float w00 = (1.0f-wx)*(1.0f-wy), w01 = wx*(1.0f-wy);
      float w10 = (1.0f-wx)*wy,        w11 = wx*wy;
      const size_t HW = (size_t)R*R;
      const float* b00f = (const float*)pp.p[s*3+p] + (size_t)y0*R + x0;
      #pragma unroll 4
      for (int c=0; c<32; c++){
        const float* q = b00f + (size_t)c*HW;
        float val = q[0]*w00 + q[1]*w01 + q[R]*w10 + q[R+1]*w11;
        prod[c] = (p == 0) ? val : prod[c]*val;
      }
    }
    #pragma unroll
    for (int vv=0; vv<4; vv++){
      short8 pk8;
      #pragma unroll
      for (int e=0; e<8; e++) pk8[e] = (short)f2h(prod[vv*8+e]);
      *(short8*)(feats + (size_t)n*96 + s*32 + vv*8) = pk8;
    }
  }
}

// ---------------- fused MLP (fp16 MFMA, A=weights B=activations^T)
// X (double-buffered) holds activations [64 points][256 feat] f16,
//   byte addr = (pt*512 + feat*2) ^ ((pt&7)<<4)
// A-fragments from fragment-ordered weights; B-fragments read X.
// acc[rf][cf]: rf = out-feature block (row), cf = point block (col).
// C-layout: col=point=lane&15, row=feature=(lane>>4)*4+r  ->  each lane's
// 4 acc values are 4 consecutive features of one point -> ds_write_b64.
// ks loop NOT unrolled (arch-VGPR budget ~128 at 2 waves/SIMD; R3/R4 spilled).
template<int KSTEPS>
__device__ __forceinline__ void mm_tile(const u16* X, const u16* __restrict__ WTs,
                                        int ftbase, int lane, floatx4 acc[4][4])
{
  const int lr = lane & 15, lg = lane >> 4;
  #pragma unroll
  for (int rf=0; rf<4; rf++)
    #pragma unroll
    for (int cf=0; cf<4; cf++)
      acc[rf][cf] = (floatx4){0.0f, 0.0f, 0.0f, 0.0f};
  #pragma unroll 1
  for (int ks=0; ks<KSTEPS; ks++){
    half8 w[4];
    #pragma unroll
    for (int rf=0; rf<4; rf++)
      w[rf] = *(const half8*)(WTs + ((size_t)((ftbase+rf)*KSTEPS + ks)*64 + lane)*8);
    half8 x[4];
    #pragma unroll
    for (int cf=0; cf<4; cf++){
      int pt = cf*16 + lr;
      int byt = (pt*512 + (ks*32 + lg*8)*2) ^ ((pt & 7) << 4);
      x[cf] = *(const half8*)((const char*)X + byt);
    }
    __builtin_amdgcn_s_setprio(1);
    #pragma unroll
    for (int rf=0; rf<4; rf++)
      #pragma unroll
      for (int cf=0; cf<4; cf++)
        acc[rf][cf] = __builtin_amdgcn_mfma_f32_16x16x32_f16(w[rf], x[cf], acc[rf][cf], 0, 0, 0);
    __builtin_amdgcn_s_setprio(0);
  }
}

__global__ __launch_bounds__(256, 2) void mlp_kernel(
    const u16* __restrict__ feats,
    const u16* __restrict__ l0T, const u16* __restrict__ resT, const u16* __restrict__ l1T,
    const float* __restrict__ l0_b, const float* __restrict__ res_b, const float* __restrict__ l1_b,
    float* __restrict__ out)
{
  __shared__ u16 Xb[2][64*256];
  const int tid = threadIdx.x;
  const int wave = tid >> 6, lane = tid & 63;
  const int lr = lane & 15, lg = lane >> 4;
  const int n0 = blockIdx.x * 64;
  const int ftbase = wave * 4;          // out-feature-tile base (16 feats per ft)
  const int wb = wave * 64;             // out-feature base

  // stage feats tile into buf0: 64 points x 96 feat f16
  #pragma unroll
  for (int i=0; i<3; i++){
    int id = tid + i*256;
    int row = id / 12, sub = id - row*12;
    short8 v = *(const short8*)(feats + (size_t)(n0+row)*96 + sub*8);
    int byt = (row*512 + sub*16) ^ ((row & 7) << 4);
    *(short8*)((char*)Xb[0] + byt) = v;
  }
  __syncthreads();

  floatx4 acc[4][4];
  u32 pk[4][4][2];   // current x tile, packed f16 feature-pairs (f,f+1 | f+2,f+3)
  int cur = 0;

  // ---- L0: K=96, no activation.  read buf0 -> write buf1
  mm_tile<3>(Xb[0], l0T, ftbase, lane, acc);
  {
    char* Xw = (char*)Xb[1];
    #pragma unroll
    for (int rf=0; rf<4; rf++){
      float4 bb = *(const float4*)(l0_b + wb + rf*16 + lg*4);
      int fby = (wb + rf*16 + lg*4)*2;
      #pragma unroll
      for (int cf=0; cf<4; cf++){
        int pt = cf*16 + lr;
        u32 p0 = pkrtz(acc[rf][cf][0] + bb.x, acc[rf][cf][1] + bb.y);
        u32 p1 = pkrtz(acc[rf][cf][2] + bb.z, acc[rf][cf][3] + bb.w);
        pk[rf][cf][0] = p0; pk[rf][cf][1] = p1;
        int byt = (pt*512 + fby) ^ ((pt & 7) << 4);
        *(u32x2*)(Xw + byt) = (u32x2){p0, p1};
      }
    }
  }
  __syncthreads();
  cur = 1;

  // ---- 3 ResBlocks; each layer: read Xb[cur] -> write Xb[cur^1], 1 barrier
  for (int rb=0; rb<3; rb++){
    const u16* W0 = resT + (size_t)(rb*3+0)*65536;
    const u16* W1 = resT + (size_t)(rb*3+1)*65536;
    const u16* W2 = resT + (size_t)(rb*3+2)*65536;
    const float* b0 = res_b + (rb*3+0)*256;
    const float* b1 = res_b + (rb*3+1)*256;
    const float* b2 = res_b + (rb*3+2)*256;

    // res = x + relu(x@W0+b0): x comes from pk (no LDS re-read)
    mm_tile<8>(Xb[cur], W0, ftbase, lane, acc);
    {
      char* Xw = (char*)Xb[cur^1];
      #pragma unroll
      for (int rf=0; rf<4; rf++){
        float4 bb = *(const float4*)(b0 + wb + rf*16 + lg*4);
        int fby = (wb + rf*16 + lg*4)*2;
        #pragma unroll
        for (int cf=0; cf<4; cf++){
          int pt = cf*16 + lr;
          half2v x01 = __builtin_bit_cast(half2v, pk[rf][cf][0]);
          half2v x23 = __builtin_bit_cast(half2v, pk[rf][cf][1]);
          float v0 = (float)x01[0] + fmaxf(acc[rf][cf][0] + bb.x, 0.0f);
          float v1 = (float)x01[1] + fmaxf(acc[rf][cf][1] + bb.y, 0.0f);
          float v2 = (float)x23[0] + fmaxf(acc[rf][cf][2] + bb.z, 0.0f);
          float v3 = (float)x23[1] + fmaxf(acc[rf][cf][3] + bb.w, 0.0f);
          u32 p0 = pkrtz(v0, v1), p1 = pkrtz(v2, v3);
          pk[rf][cf][0] = p0; pk[rf][cf][1] = p1;   // pk now holds res
          int byt = (pt*512 + fby) ^ ((pt & 7) << 4);
          *(u32x2*)(Xw + byt) = (u32x2){p0, p1};
        }
      }
    }
    __syncthreads();
    cur ^= 1;

    // x = relu(res@W1+b1) -> LDS only
    mm_tile<8>(Xb[cur], W1, ftbase, lane, acc);
    {
      char* Xw = (char*)Xb[cur^1];
      #pragma unroll
      for (int rf=0; rf<4; rf++){
        float4 bb = *(const float4*)(b1 + wb + rf*16 + lg*4);
        int fby = (wb + rf*16 + lg*4)*2;
        #pragma unroll
        for (int cf=0; cf<4; cf++){
          int pt = cf*16 + lr;
          u32 p0 = pkrtz(fmaxf(acc[rf][cf][0] + bb.x, 0.0f), fmaxf(acc[rf][cf][1] + bb.y, 0.0f));
          u32 p1 = pkrtz(fmaxf(acc[rf][cf][2] + bb.z, 0.0f), fmaxf(acc[rf][cf][3] + bb.w, 0.0f));
          int byt = (pt*512 + fby) ^ ((pt & 7) << 4);
          *(u32x2*)(Xw + byt) = (u32x2){p0, p1};
        }
      }
    }
    __syncthreads();
    cur ^= 1;

    // x = relu(x@W2+b2) + res(pk)
    mm_tile<8>(Xb[cur], W2, ftbase, lane, acc);
    {
      char* Xw = (char*)Xb[cur^1];
      #pragma unroll
      for (int rf=0; rf<4; rf++){
        float4 bb = *(const float4*)(b2 + wb + rf*16 + lg*4);
        int fby = (wb + rf*16 + lg*4)*2;
        #pragma unroll
        for (int cf=0; cf<4; cf++){
          int pt = cf*16 + lr;
          half2v r01 = __builtin_bit_cast(half2v, pk[rf][cf][0]);
          half2v r23 = __builtin_bit_cast(half2v, pk[rf][cf][1]);
          float v0 = fmaxf(acc[rf][cf][0] + bb.x, 0.0f) + (float)r01[0];
          float v1 = fmaxf(acc[rf][cf][1] + bb.y, 0.0f) + (float)r01[1];
          float v2 = fmaxf(acc[rf][cf][2] + bb.z, 0.0f) + (float)r23[0];
          float v3 = fmaxf(acc[rf][cf][3] + bb.w, 0.0f) + (float)r23[1];
          u32 p0 = pkrtz(v0, v1), p1 = pkrtz(v2, v3);
          pk[rf][cf][0] = p0; pk[rf][cf][1] = p1;   // pk now holds new x
          int byt = (pt*512 + fby) ^ ((pt & 7) << 4);
          *(u32x2*)(Xw + byt) = (u32x2){p0, p1};
        }
      }
    }
    __syncthreads();
    cur ^= 1;
  }

  // ---- final: 256 -> 16, sigmoid. Wave w: points w*16..w*16+15, 16 feats.
  floatx4 accf = {0.0f, 0.0f, 0.0f, 0.0f};
  const char* Xr = (const char*)Xb[cur];
  #pragma unroll 1
  for (int ks=0; ks<8; ks++){
    int pt = wave*16 + lr;
    int byt = (pt*512 + (ks*32 + lg*8)*2) ^ ((pt&7)<<4);
    half8 x = *(const half8*)(Xr + byt);
    half8 w = *(const half8*)(l1T + ((size_t)ks*64 + lane)*8);
    accf = __builtin_amdgcn_mfma_f32_16x16x32_f16(w, x, accf, 0, 0, 0);
  }
  {
    float4 bo = *(const float4*)(l1_b + lg*4);
    float4 o;
    o.x = 1.0f / (1.0f + __expf(-(accf[0] + bo.x)));
    o.y = 1.0f / (1.0f + __expf(-(accf[1] + bo.y)));
    o.z = 1.0f / (1.0f + __expf(-(accf[2] + bo.z)));
    o.w = 1.0f / (1.0f + __expf(-(accf[3] + bo.w)));
    *(float4*)(out + (size_t)(n0 + wave*16 + lr)*16 + lg*4) = o;
  }
}

// ---------------- host
extern "C" void kernel_launch(void* const* d_in, const int* in_sizes, int n_in,
                              void* d_out, int out_size, void* d_ws, size_t ws_size,
                              hipStream_t stream)
{
  const float* pts  = (const float*)d_in[0];
  const float* aabb = (const float*)d_in[1];
  const float* l0_w = (const float*)d_in[11];
  const float* res_w= (const float*)d_in[13];
  const float* l1_w = (const float*)d_in[15];
  const float* l0_b = (const float*)d_in[12];
  const float* res_b= (const float*)d_in[14];
  const float* l1_b = (const float*)d_in[16];
  const int N = in_sizes[0] / 3;

  char* ws = (char*)d_ws;
  const size_t woff_l0  = 0;                          // 256*96*2
  const size_t woff_res = 49152;                      // 9*65536*2
  const size_t woff_l1  = woff_res + 9*65536*2;       // 16*256*2
  const size_t foff     = woff_l1 + 8192;             // feats: N*96*2
  const size_t poff     = foff + (size_t)N*96*2;      // f16 planes

  static const int HWs[3] = {128*128, 256*256, 512*512};
  size_t pel[9]; size_t tot = 0;
  for (int s=0;s<3;s++) for (int p=0;p<3;p++){ pel[s*3+p] = tot; tot += (size_t)HWs[s]*32; }

  const bool tr_mode = (ws_size >= poff + tot*2);

  // weights -> fragment-ordered f16
  wconv_kernel<<<(24576+255)/256,  256, 0, stream>>>(l0_w, (u16*)(ws+woff_l0), 96, 256, 24576);
  wconv_kernel<<<(589824+255)/256, 256, 0, stream>>>(res_w,(u16*)(ws+woff_res),256, 256, 589824);
  wconv_kernel<<<(4096+255)/256,   256, 0, stream>>>(l1_w, (u16*)(ws+woff_l1), 256, 16,  4096);

  PlanePtrs pp;
  if (tr_mode){
    u16* pbase = (u16*)(ws + poff);
    for (int i=0;i<9;i++){
      int s = i/3;
      ptrans_kernel<<<HWs[s]/256, 256, 0, stream>>>((const float*)d_in[2+i], pbase + pel[i], HWs[s]);
      pp.p[i] = pbase + pel[i];
    }
    interp4_kernel<<<(4*N+255)/256, 256, 0, stream>>>(pts, aabb, pp, (u16*)(ws+foff), N);
  } else {
    for (int i=0;i<9;i++) pp.p[i] = d_in[2+i];
    interp_fb_kernel<<<(N+255)/256, 256, 0, stream>>>(pts, aabb, pp, (u16*)(ws+foff), N);
  }

  mlp_kernel<<<N/64, 256, 0, stream>>>((const u16*)(ws+foff),
      (const u16*)(ws+woff_l0), (const u16*)(ws+woff_res), (const u16*)(ws+woff_l1),
      l0_b, res_b, l1_b, (float*)d_out);
}

// Round 8
// 270.915 us; speedup vs baseline: 3.8391x; 1.0367x over previous
//
#include <hip/hip_runtime.h>

typedef unsigned short u16;
typedef unsigned int u32;
typedef __attribute__((ext_vector_type(2))) unsigned int u32x2;
typedef __attribute__((ext_vector_type(8))) short short8;
typedef __attribute__((ext_vector_type(8))) _Float16 half8;
typedef __attribute__((ext_vector_type(2))) __fp16 fp16x2;
typedef __attribute__((ext_vector_type(4))) float floatx4;

__device__ __forceinline__ u16 f2h(float f){ _Float16 h = (_Float16)f; return __builtin_bit_cast(u16, h); }
__device__ __forceinline__ u32 pkrtz(float a, float b){
  fp16x2 h = __builtin_amdgcn_cvt_pkrtz(a, b);
  return __builtin_bit_cast(u32, h);
}
// packed f16 relu / add (VOP3P)
__device__ __forceinline__ u32 pkmax0(u32 a){
  u32 d, z = 0;
  asm("v_pk_max_f16 %0, %1, %2" : "=v"(d) : "v"(a), "v"(z));
  return d;
}
__device__ __forceinline__ u32 pkadd(u32 a, u32 b){
  u32 d;
  asm("v_pk_add_f16 %0, %1, %2" : "=v"(d) : "v"(a), "v"(b));
  return d;
}

// ---------------- prep: plane transpose [C=32][HW] f32 -> [HW][C] f16
__global__ void ptrans_kernel(const float* __restrict__ src, u16* __restrict__ dst, int HW){
  __shared__ float tile[32][257];
  const int t = threadIdx.x;
  const size_t hw0 = (size_t)blockIdx.x * 256;
  #pragma unroll
  for (int c = 0; c < 32; c++) tile[c][t] = src[(size_t)c*HW + hw0 + t];
  __syncthreads();
  u32* d32 = (u32*)(dst + hw0*32);
  #pragma unroll
  for (int i = 0; i < 16; i++){
    int idx = i*512 + t*2;
    int j = idx >> 5, cc = idx & 31;
    u32 lo = f2h(tile[cc][j]);
    u32 hi = f2h(tile[cc+1][j]);
    d32[i*256 + t] = lo | (hi << 16);
  }
}

// ---------------- prep: weights -> MFMA A-fragment order f16
// Logical A[of][k] = src[m][k][of]; stored dst[m][ft][ks][lane][e]:
//   of = ft*16 + (lane&15), k = ks*32 + (lane>>4)*8 + e
__global__ void wconv_kernel(const float* __restrict__ src, u16* __restrict__ dst,
                             int fin, int fout, int total){
  int t = blockIdx.x*256 + threadIdx.x;
  if (t >= total) return;
  int per = fin * fout;
  int m = t / per, r = t - m*per;
  int KS = fin >> 5;
  int e = r & 7;
  int lane = (r >> 3) & 63;
  int fs = r >> 9;                 // fragment-slot: ft*KS + ks
  int ks = fs % KS, ft = fs / KS;
  int of = ft*16 + (lane & 15);
  int k  = ks*32 + (lane >> 4)*8 + e;
  dst[t] = f2h(src[(size_t)m*per + (size_t)k*fout + of]);
}

// ---------------- interpolation
struct PlanePtrs { const void* p[9]; };

// 4 threads per point; thread (n, v) handles channels v*8..v*8+7.
__global__ void interp4_kernel(const float* __restrict__ pts, const float* __restrict__ aabb,
                               PlanePtrs pp, u16* __restrict__ feats, int N)
{
  int g = blockIdx.x*256 + threadIdx.x;
  int n = g >> 2, v = g & 3;
  if (n >= N) return;
  float xn[3];
  #pragma unroll
  for (int d=0; d<3; d++){
    float lo = aabb[d], hi = aabb[3+d];
    xn[d] = (pts[(size_t)n*3 + d] - lo) * (2.0f/(hi - lo)) - 1.0f;
  }
  const int c0s[3] = {0,0,1};
  const int c1s[3] = {1,2,2};
  #pragma unroll
  for (int s=0; s<3; s++){
    const int R = 128 << s;
    float prod[8];
    #pragma unroll
    for (int p=0; p<3; p++){
      float fx = (xn[c0s[p]] + 1.0f) * 0.5f * (float)(R-1);
      float fy = (xn[c1s[p]] + 1.0f) * 0.5f * (float)(R-1);
      float fx0 = fminf(fmaxf(floorf(fx), 0.0f), (float)(R-2));
      float fy0 = fminf(fmaxf(floorf(fy), 0.0f), (float)(R-2));
      int x0 = (int)fx0, y0 = (int)fy0;
      float wx = fx - fx0, wy = fy - fy0;
      float w00 = (1.0f-wx)*(1.0f-wy), w01 = wx*(1.0f-wy);
      float w10 = (1.0f-wx)*wy,        w11 = wx*wy;
      const u16* base = (const u16*)pp.p[s*3 + p];
      const u16* b00 = base + ((size_t)y0*R + x0)*32 + v*8;
      const u16* b10 = b00 + (size_t)R*32;
      half8 h00 = *(const half8*)b00;
      half8 h01 = *(const half8*)(b00 + 32);
      half8 h10 = *(const half8*)b10;
      half8 h11 = *(const half8*)(b10 + 32);
      #pragma unroll
      for (int e=0; e<8; e++){
        float val = (float)h00[e]*w00 + (float)h01[e]*w01 + (float)h10[e]*w10 + (float)h11[e]*w11;
        prod[e] = (p == 0) ? val : prod[e]*val;
      }
    }
    short8 pk8;
    #pragma unroll
    for (int e=0; e<8; e++) pk8[e] = (short)f2h(prod[e]);
    *(short8*)(feats + (size_t)n*96 + s*32 + v*8) = pk8;
  }
}

// fallback: 1-thread/point gather from untransposed planes
__global__ void interp_fb_kernel(const float* __restrict__ pts, const float* __restrict__ aabb,
                                 PlanePtrs pp, u16* __restrict__ feats, int N)
{
  int n = blockIdx.x*256 + threadIdx.x;
  if (n >= N) return;
  float xn[3];
  #pragma unroll
  for (int d=0; d<3; d++){
    float lo = aabb[d], hi = aabb[3+d];
    xn[d] = (pts[(size_t)n*3 + d] - lo) * (2.0f/(hi - lo)) - 1.0f;
  }
  const int c0s[3] = {0,0,1};
  const int c1s[3] = {1,2,2};
  #pragma unroll
  for (int s=0; s<3; s++){
    const int R = 128 << s;
    float prod[32];
    #pragma unroll
    for (int p=0; p<3; p++){
      float fx = (xn[c0s[p]] + 1.0f) * 0.5f * (float)(R-1);
      float fy = (xn[c1s[p]] + 1.0f) * 0.5f * (float)(R-1);
      float fx0 = fminf(fmaxf(floorf(fx), 0.0f), (float)(R-2));
      float fy0 = fminf(fmaxf(floorf(fy), 0.0f), (float)(R-2));
      int x0 = (int)fx0, y0 = (int)fy0;
      float wx = fx - fx0, wy = fy - fy0;
      float w00 = (1.0f-wx)*(1.0f-wy), w01 = wx*(1.0f-wy);
      float w10 = (1.0f-wx)*wy,        w11 = wx*wy;
      const size_t HW = (size_t)R*R;
      const float* b00f = (const float*)pp.p[s*3+p] + (size_t)y0*R + x0;
      #pragma unroll 4
      for (int c=0; c<32; c++){
        const float* q = b00f + (size_t)c*HW;
        float val = q[0]*w00 + q[1]*w01 + q[R]*w10 + q[R+1]*w11;
        prod[c] = (p == 0) ? val : prod[c]*val;
      }
    }
    #pragma unroll
    for (int vv=0; vv<4; vv++){
      short8 pk8;
      #pragma unroll
      for (int e=0; e<8; e++) pk8[e] = (short)f2h(prod[vv*8+e]);
      *(short8*)(feats + (size_t)n*96 + s*32 + vv*8) = pk8;
    }
  }
}

// ---------------- fused MLP (fp16 MFMA, A=weights B=activations^T)
// X (double-buffered) holds activations [64 points][256 feat] f16,
//   byte addr = (pt*512 + feat*2) ^ ((pt&7)<<4)
// acc[rf][cf]: rf = out-feature block, cf = point block.
// C-layout: col=point=lane&15, row=feature=(lane>>4)*4+r -> each lane's
// 4 acc values = 4 consecutive features of one point -> ds_write_b64.
// Bias is folded into acc init (MFMA C-in is free).
// ks loop NOT unrolled (arch-VGPR budget ~192 at 2 waves/SIMD; R3/R4 spilled).
template<int KSTEPS>
__device__ __forceinline__ void mm_tile(const u16* X, const u16* __restrict__ WTs,
                                        int ftbase, int lane, const floatx4 binit[4],
                                        floatx4 acc[4][4])
{
  const int lr = lane & 15, lg = lane >> 4;
  #pragma unroll
  for (int rf=0; rf<4; rf++)
    #pragma unroll
    for (int cf=0; cf<4; cf++)
      acc[rf][cf] = binit[rf];
  #pragma unroll 1
  for (int ks=0; ks<KSTEPS; ks++){
    half8 w[4];
    #pragma unroll
    for (int rf=0; rf<4; rf++)
      w[rf] = *(const half8*)(WTs + ((size_t)((ftbase+rf)*KSTEPS + ks)*64 + lane)*8);
    half8 x[4];
    #pragma unroll
    for (int cf=0; cf<4; cf++){
      int pt = cf*16 + lr;
      int byt = (pt*512 + (ks*32 + lg*8)*2) ^ ((pt & 7) << 4);
      x[cf] = *(const half8*)((const char*)X + byt);
    }
    __builtin_amdgcn_s_setprio(1);
    #pragma unroll
    for (int rf=0; rf<4; rf++)
      #pragma unroll
      for (int cf=0; cf<4; cf++)
        acc[rf][cf] = __builtin_amdgcn_mfma_f32_16x16x32_f16(w[rf], x[cf], acc[rf][cf], 0, 0, 0);
    __builtin_amdgcn_s_setprio(0);
  }
}

__device__ __forceinline__ void load_binit(const float* b, int wb, int rf16, int lg, floatx4* bi){
  #pragma unroll
  for (int rf=0; rf<4; rf++){
    float4 v = *(const float4*)(b + wb + rf*16 + lg*4);
    bi[rf] = (floatx4){v.x, v.y, v.z, v.w};
  }
  (void)rf16;
}

__global__ __launch_bounds__(256, 2) void mlp_kernel(
    const u16* __restrict__ feats,
    const u16* __restrict__ l0T, const u16* __restrict__ resT, const u16* __restrict__ l1T,
    const float* __restrict__ l0_b, const float* __restrict__ res_b, const float* __restrict__ l1_b,
    float* __restrict__ out)
{
  __shared__ u16 Xb[2][64*256];
  const int tid = threadIdx.x;
  const int wave = tid >> 6, lane = tid & 63;
  const int lr = lane & 15, lg = lane >> 4;
  const int n0 = blockIdx.x * 64;
  const int ftbase = wave * 4;          // out-feature-tile base (16 feats per ft)
  const int wb = wave * 64;             // out-feature base

  // stage feats tile into buf0: 64 points x 96 feat f16
  #pragma unroll
  for (int i=0; i<3; i++){
    int id = tid + i*256;
    int row = id / 12, sub = id - row*12;
    short8 v = *(const short8*)(feats + (size_t)(n0+row)*96 + sub*8);
    int byt = (row*512 + sub*16) ^ ((row & 7) << 4);
    *(short8*)((char*)Xb[0] + byt) = v;
  }
  __syncthreads();

  floatx4 acc[4][4];
  floatx4 binit[4];
  u32 pk[4][4][2];   // current x tile, packed f16 feature-pairs (f,f+1 | f+2,f+3)
  int cur = 0;

  // ---- L0: K=96, no activation.  read buf0 -> write buf1
  load_binit(l0_b, wb, 0, lg, binit);
  mm_tile<3>(Xb[0], l0T, ftbase, lane, binit, acc);
  {
    char* Xw = (char*)Xb[1];
    #pragma unroll
    for (int rf=0; rf<4; rf++){
      int fby = (wb + rf*16 + lg*4)*2;
      #pragma unroll
      for (int cf=0; cf<4; cf++){
        int pt = cf*16 + lr;
        u32 p0 = pkrtz(acc[rf][cf][0], acc[rf][cf][1]);
        u32 p1 = pkrtz(acc[rf][cf][2], acc[rf][cf][3]);
        pk[rf][cf][0] = p0; pk[rf][cf][1] = p1;
        int byt = (pt*512 + fby) ^ ((pt & 7) << 4);
        *(u32x2*)(Xw + byt) = (u32x2){p0, p1};
      }
    }
  }
  __syncthreads();
  cur = 1;

  // ---- 3 ResBlocks; each layer: read Xb[cur] -> write Xb[cur^1], 1 barrier
  for (int rb=0; rb<3; rb++){
    const u16* W0 = resT + (size_t)(rb*3+0)*65536;
    const u16* W1 = resT + (size_t)(rb*3+1)*65536;
    const u16* W2 = resT + (size_t)(rb*3+2)*65536;
    const float* b0 = res_b + (rb*3+0)*256;
    const float* b1 = res_b + (rb*3+1)*256;
    const float* b2 = res_b + (rb*3+2)*256;

    // res = x + relu(x@W0+b0): x from pk (packed), relu+add in packed f16
    load_binit(b0, wb, 0, lg, binit);
    mm_tile<8>(Xb[cur], W0, ftbase, lane, binit, acc);
    {
      char* Xw = (char*)Xb[cur^1];
      #pragma unroll
      for (int rf=0; rf<4; rf++){
        int fby = (wb + rf*16 + lg*4)*2;
        #pragma unroll
        for (int cf=0; cf<4; cf++){
          int pt = cf*16 + lr;
          u32 p0 = pkadd(pk[rf][cf][0], pkmax0(pkrtz(acc[rf][cf][0], acc[rf][cf][1])));
          u32 p1 = pkadd(pk[rf][cf][1], pkmax0(pkrtz(acc[rf][cf][2], acc[rf][cf][3])));
          pk[rf][cf][0] = p0; pk[rf][cf][1] = p1;   // pk now holds res
          int byt = (pt*512 + fby) ^ ((pt & 7) << 4);
          *(u32x2*)(Xw + byt) = (u32x2){p0, p1};
        }
      }
    }
    __syncthreads();
    cur ^= 1;

    // x = relu(res@W1+b1) -> LDS only
    load_binit(b1, wb, 0, lg, binit);
    mm_tile<8>(Xb[cur], W1, ftbase, lane, binit, acc);
    {
      char* Xw = (char*)Xb[cur^1];
      #pragma unroll
      for (int rf=0; rf<4; rf++){
        int fby = (wb + rf*16 + lg*4)*2;
        #pragma unroll
        for (int cf=0; cf<4; cf++){
          int pt = cf*16 + lr;
          u32 p0 = pkmax0(pkrtz(acc[rf][cf][0], acc[rf][cf][1]));
          u32 p1 = pkmax0(pkrtz(acc[rf][cf][2], acc[rf][cf][3]));
          int byt = (pt*512 + fby) ^ ((pt & 7) << 4);
          *(u32x2*)(Xw + byt) = (u32x2){p0, p1};
        }
      }
    }
    __syncthreads();
    cur ^= 1;

    // x = relu(x@W2+b2) + res(pk), packed
    load_binit(b2, wb, 0, lg, binit);
    mm_tile<8>(Xb[cur], W2, ftbase, lane, binit, acc);
    {
      char* Xw = (char*)Xb[cur^1];
      #pragma unroll
      for (int rf=0; rf<4; rf++){
        int fby = (wb + rf*16 + lg*4)*2;
        #pragma unroll
        for (int cf=0; cf<4; cf++){
          int pt = cf*16 + lr;
          u32 p0 = pkadd(pkmax0(pkrtz(acc[rf][cf][0], acc[rf][cf][1])), pk[rf][cf][0]);
          u32 p1 = pkadd(pkmax0(pkrtz(acc[rf][cf][2], acc[rf][cf][3])), pk[rf][cf][1]);
          pk[rf][cf][0] = p0; pk[rf][cf][1] = p1;   // pk now holds new x
          int byt = (pt*512 + fby) ^ ((pt & 7) << 4);
          *(u32x2*)(Xw + byt) = (u32x2){p0, p1};
        }
      }
    }
    __syncthreads();
    cur ^= 1;
  }

  // ---- final: 256 -> 16, sigmoid. Wave w: points w*16..w*16+15, 16 feats.
  floatx4 accf;
  {
    float4 bo = *(const float4*)(l1_b + lg*4);
    accf = (floatx4){bo.x, bo.y, bo.z, bo.w};
  }
  const char* Xr = (const char*)Xb[cur];
  #pragma unroll 1
  for (int ks=0; ks<8; ks++){
    int pt = wave*16 + lr;
    int byt = (pt*512 + (ks*32 + lg*8)*2) ^ ((pt&7)<<4);
    half8 x = *(const half8*)(Xr + byt);
    half8 w = *(const half8*)(l1T + ((size_t)ks*64 + lane)*8);
    accf = __builtin_amdgcn_mfma_f32_16x16x32_f16(w, x, accf, 0, 0, 0);
  }
  {
    float4 o;
    o.x = 1.0f / (1.0f + __expf(-accf[0]));
    o.y = 1.0f / (1.0f + __expf(-accf[1]));
    o.z = 1.0f / (1.0f + __expf(-accf[2]));
    o.w = 1.0f / (1.0f + __expf(-accf[3]));
    *(float4*)(out + (size_t)(n0 + wave*16 + lr)*16 + lg*4) = o;
  }
}

// ---------------- host
extern "C" void kernel_launch(void* const* d_in, const int* in_sizes, int n_in,
                              void* d_out, int out_size, void* d_ws, size_t ws_size,
                              hipStream_t stream)
{
  const float* pts  = (const float*)d_in[0];
  const float* aabb = (const float*)d_in[1];
  const float* l0_w = (const float*)d_in[11];
  const float* res_w= (const float*)d_in[13];
  const float* l1_w = (const float*)d_in[15];
  const float* l0_b = (const float*)d_in[12];
  const float* res_b= (const float*)d_in[14];
  const float* l1_b = (const float*)d_in[16];
  const int N = in_sizes[0] / 3;

  char* ws = (char*)d_ws;
  const size_t woff_l0  = 0;                          // 256*96*2
  const size_t woff_res = 49152;                      // 9*65536*2
  const size_t woff_l1  = woff_res + 9*65536*2;       // 16*256*2
  const size_t foff     = woff_l1 + 8192;             // feats: N*96*2
  const size_t poff     = foff + (size_t)N*96*2;      // f16 planes

  static const int HWs[3] = {128*128, 256*256, 512*512};
  size_t pel[9]; size_t tot = 0;
  for (int s=0;s<3;s++) for (int p=0;p<3;p++){ pel[s*3+p] = tot; tot += (size_t)HWs[s]*32; }

  const bool tr_mode = (ws_size >= poff + tot*2);

  // weights -> fragment-ordered f16
  wconv_kernel<<<(24576+255)/256,  256, 0, stream>>>(l0_w, (u16*)(ws+woff_l0), 96, 256, 24576);
  wconv_kernel<<<(589824+255)/256, 256, 0, stream>>>(res_w,(u16*)(ws+woff_res),256, 256, 589824);
  wconv_kernel<<<(4096+255)/256,   256, 0, stream>>>(l1_w, (u16*)(ws+woff_l1), 256, 16,  4096);

  PlanePtrs pp;
  if (tr_mode){
    u16* pbase = (u16*)(ws + poff);
    for (int i=0;i<9;i++){
      int s = i/3;
      ptrans_kernel<<<HWs[s]/256, 256, 0, stream>>>((const float*)d_in[2+i], pbase + pel[i], HWs[s]);
      pp.p[i] = pbase + pel[i];
    }
    interp4_kernel<<<(4*N+255)/256, 256, 0, stream>>>(pts, aabb, pp, (u16*)(ws+foff), N);
  } else {
    for (int i=0;i<9;i++) pp.p[i] = d_in[2+i];
    interp_fb_kernel<<<(N+255)/256, 256, 0, stream>>>(pts, aabb, pp, (u16*)(ws+foff), N);
  }

  mlp_kernel<<<N/64, 256, 0, stream>>>((const u16*)(ws+foff),
      (const u16*)(ws+woff_l0), (const u16*)(ws+woff_res), (const u16*)(ws+woff_l1),
      l0_b, res_b, l1_b, (float*)d_out);
}

// Round 9
// 252.293 us; speedup vs baseline: 4.1225x; 1.0738x over previous
//
#include <hip/hip_runtime.h>

typedef unsigned short u16;
typedef unsigned int u32;
typedef __attribute__((ext_vector_type(2))) unsigned int u32x2;
typedef __attribute__((ext_vector_type(8))) short short8;
typedef __attribute__((ext_vector_type(8))) _Float16 half8;
typedef __attribute__((ext_vector_type(2))) __fp16 fp16x2;
typedef __attribute__((ext_vector_type(4))) float floatx4;

__device__ __forceinline__ u16 f2h(float f){ _Float16 h = (_Float16)f; return __builtin_bit_cast(u16, h); }
__device__ __forceinline__ u32 pkrtz(float a, float b){
  fp16x2 h = __builtin_amdgcn_cvt_pkrtz(a, b);
  return __builtin_bit_cast(u32, h);
}
// packed f16 relu / add (VOP3P)
__device__ __forceinline__ u32 pkmax0(u32 a){
  u32 d, z = 0;
  asm("v_pk_max_f16 %0, %1, %2" : "=v"(d) : "v"(a), "v"(z));
  return d;
}
__device__ __forceinline__ u32 pkadd(u32 a, u32 b){
  u32 d;
  asm("v_pk_add_f16 %0, %1, %2" : "=v"(d) : "v"(a), "v"(b));
  return d;
}

struct PlanePtrs { const void* p[9]; };
struct PtransArgs { const float* src[9]; u16* dst[9]; int blk0[10]; int HW[9]; };

// ---------------- prep: all 9 plane transposes in one launch
// [C=32][HW] f32 -> [HW][C] f16
__global__ void ptrans_all_kernel(PtransArgs a){
  __shared__ float tile[32][257];
  int bi = blockIdx.x;
  int i = 0;
  #pragma unroll
  for (int k = 1; k < 9; k++) if (bi >= a.blk0[k]) i = k;
  const float* src = a.src[i];
  u16* dst = a.dst[i];
  const int HW = a.HW[i];
  const int t = threadIdx.x;
  const size_t hw0 = (size_t)(bi - a.blk0[i]) * 256;
  #pragma unroll
  for (int c = 0; c < 32; c++) tile[c][t] = src[(size_t)c*HW + hw0 + t];
  __syncthreads();
  u32* d32 = (u32*)(dst + hw0*32);
  #pragma unroll
  for (int k = 0; k < 16; k++){
    int idx = k*512 + t*2;
    int j = idx >> 5, cc = idx & 31;
    u32 lo = f2h(tile[cc][j]);
    u32 hi = f2h(tile[cc+1][j]);
    d32[k*256 + t] = lo | (hi << 16);
  }
}

// ---------------- prep: all weights -> MFMA A-fragment order f16, one launch
// Logical A[of][k] = src[m][k][of]; stored dst[m][ft][ks][lane][e]:
//   of = ft*16 + (lane&15), k = ks*32 + (lane>>4)*8 + e
__device__ __forceinline__ void wconv_one(const float* src, u16* dst, int fin, int fout, int t){
  int per = fin * fout;
  int m = t / per, r = t - m*per;
  int KS = fin >> 5;
  int e = r & 7;
  int lane = (r >> 3) & 63;
  int fs = r >> 9;
  int ks = fs % KS, ft = fs / KS;
  int of = ft*16 + (lane & 15);
  int k  = ks*32 + (lane >> 4)*8 + e;
  dst[t] = f2h(src[(size_t)m*per + (size_t)k*fout + of]);
}
__global__ void wconv_all_kernel(const float* l0_w, const float* res_w, const float* l1_w,
                                 u16* l0T, u16* resT, u16* l1T){
  int t = blockIdx.x*256 + threadIdx.x;           // total 24576 + 589824 + 4096
  if (t < 24576){ wconv_one(l0_w, l0T, 96, 256, t); return; }
  t -= 24576;
  if (t < 589824){ wconv_one(res_w, resT, 256, 256, t); return; }
  t -= 589824;
  if (t < 4096){ wconv_one(l1_w, l1T, 256, 16, t); }
}

// ---------------- standalone interp fallback (untransposed planes -> feats)
__global__ void interp_fb_kernel(const float* __restrict__ pts, const float* __restrict__ aabb,
                                 PlanePtrs pp, u16* __restrict__ feats, int N)
{
  int n = blockIdx.x*256 + threadIdx.x;
  if (n >= N) return;
  float xn[3];
  #pragma unroll
  for (int d=0; d<3; d++){
    float lo = aabb[d], hi = aabb[3+d];
    xn[d] = (pts[(size_t)n*3 + d] - lo) * (2.0f/(hi - lo)) - 1.0f;
  }
  const int c0s[3] = {0,0,1};
  const int c1s[3] = {1,2,2};
  #pragma unroll
  for (int s=0; s<3; s++){
    const int R = 128 << s;
    float prod[32];
    #pragma unroll
    for (int p=0; p<3; p++){
      float fx = (xn[c0s[p]] + 1.0f) * 0.5f * (float)(R-1);
      float fy = (xn[c1s[p]] + 1.0f) * 0.5f * (float)(R-1);
      float fx0 = fminf(fmaxf(floorf(fx), 0.0f), (float)(R-2));
      float fy0 = fminf(fmaxf(floorf(fy), 0.0f), (float)(R-2));
      int x0 = (int)fx0, y0 = (int)fy0;
      float wx = fx - fx0, wy = fy - fy0;
      float w00 = (1.0f-wx)*(1.0f-wy), w01 = wx*(1.0f-wy);
      float w10 = (1.0f-wx)*wy,        w11 = wx*wy;
      const size_t HW = (size_t)R*R;
      const float* b00f = (const float*)pp.p[s*3+p] + (size_t)y0*R + x0;
      #pragma unroll 4
      for (int c=0; c<32; c++){
        const float* q = b00f + (size_t)c*HW;
        float val = q[0]*w00 + q[1]*w01 + q[R]*w10 + q[R+1]*w11;
        prod[c] = (p == 0) ? val : prod[c]*val;
      }
    }
    #pragma unroll
    for (int vv=0; vv<4; vv++){
      short8 pk8;
      #pragma unroll
      for (int e=0; e<8; e++) pk8[e] = (short)f2h(prod[vv*8+e]);
      *(short8*)(feats + (size_t)n*96 + s*32 + vv*8) = pk8;
    }
  }
}

// ---------------- fused gather + MLP (fp16 MFMA, A=weights B=activations^T)
// X (double-buffered) holds activations [64 points][256 feat] f16,
//   byte addr = (pt*512 + feat*2) ^ ((pt&7)<<4)
// acc[rf][cf]: rf = out-feature block, cf = point block.
// Bias folded into acc init. ks loop NOT unrolled (arch-VGPR budget ~ total 256
// at 2 waves/SIMD incl. AGPR acc; R3/R4 over-unroll spilled).
template<int KSTEPS>
__device__ __forceinline__ void mm_tile(const u16* X, const u16* __restrict__ WTs,
                                        int ftbase, int lane, const floatx4 binit[4],
                                        floatx4 acc[4][4])
{
  const int lr = lane & 15, lg = lane >> 4;
  #pragma unroll
  for (int rf=0; rf<4; rf++)
    #pragma unroll
    for (int cf=0; cf<4; cf++)
      acc[rf][cf] = binit[rf];
  #pragma unroll 1
  for (int ks=0; ks<KSTEPS; ks++){
    half8 w[4];
    #pragma unroll
    for (int rf=0; rf<4; rf++)
      w[rf] = *(const half8*)(WTs + ((size_t)((ftbase+rf)*KSTEPS + ks)*64 + lane)*8);
    half8 x[4];
    #pragma unroll
    for (int cf=0; cf<4; cf++){
      int pt = cf*16 + lr;
      int byt = (pt*512 + (ks*32 + lg*8)*2) ^ ((pt & 7) << 4);
      x[cf] = *(const half8*)((const char*)X + byt);
    }
    __builtin_amdgcn_s_setprio(1);
    #pragma unroll
    for (int rf=0; rf<4; rf++)
      #pragma unroll
      for (int cf=0; cf<4; cf++)
        acc[rf][cf] = __builtin_amdgcn_mfma_f32_16x16x32_f16(w[rf], x[cf], acc[rf][cf], 0, 0, 0);
    __builtin_amdgcn_s_setprio(0);
  }
}

__device__ __forceinline__ void load_binit(const float* b, int wb, int lg, floatx4* bi){
  #pragma unroll
  for (int rf=0; rf<4; rf++){
    float4 v = *(const float4*)(b + wb + rf*16 + lg*4);
    bi[rf] = (floatx4){v.x, v.y, v.z, v.w};
  }
}

template<bool GATHER>
__global__ __launch_bounds__(256, 2) void mlp_kernel(
    const float* __restrict__ pts, const float* __restrict__ aabb, PlanePtrs pp,
    const u16* __restrict__ feats,
    const u16* __restrict__ l0T, const u16* __restrict__ resT, const u16* __restrict__ l1T,
    const float* __restrict__ l0_b, const float* __restrict__ res_b, const float* __restrict__ l1_b,
    float* __restrict__ out)
{
  __shared__ u16 Xb[2][64*256];
  const int tid = threadIdx.x;
  const int wave = tid >> 6, lane = tid & 63;
  const int lr = lane & 15, lg = lane >> 4;
  const int n0 = blockIdx.x * 64;
  const int ftbase = wave * 4;
  const int wb = wave * 64;

  if constexpr (GATHER){
    // ---- fused interp: 4 threads/point, thread (pt, v) -> channels v*8..v*8+7
    const int pt = tid >> 2, v = tid & 3;
    const int n = n0 + pt;
    float xn[3];
    #pragma unroll
    for (int d=0; d<3; d++){
      float lo = aabb[d], hi = aabb[3+d];
      xn[d] = (pts[(size_t)n*3 + d] - lo) * (2.0f/(hi - lo)) - 1.0f;
    }
    const int c0s[3] = {0,0,1};
    const int c1s[3] = {1,2,2};
    #pragma unroll
    for (int s=0; s<3; s++){
      const int R = 128 << s;
      float prod[8];
      #pragma unroll
      for (int p=0; p<3; p++){
        float fx = (xn[c0s[p]] + 1.0f) * 0.5f * (float)(R-1);
        float fy = (xn[c1s[p]] + 1.0f) * 0.5f * (float)(R-1);
        float fx0 = fminf(fmaxf(floorf(fx), 0.0f), (float)(R-2));
        float fy0 = fminf(fmaxf(floorf(fy), 0.0f), (float)(R-2));
        int x0 = (int)fx0, y0 = (int)fy0;
        float wx = fx - fx0, wy = fy - fy0;
        float w00 = (1.0f-wx)*(1.0f-wy), w01 = wx*(1.0f-wy);
        float w10 = (1.0f-wx)*wy,        w11 = wx*wy;
        const u16* base = (const u16*)pp.p[s*3 + p];
        const u16* b00 = base + ((size_t)y0*R + x0)*32 + v*8;
        const u16* b10 = b00 + (size_t)R*32;
        half8 h00 = *(const half8*)b00;
        half8 h01 = *(const half8*)(b00 + 32);
        half8 h10 = *(const half8*)b10;
        half8 h11 = *(const half8*)(b10 + 32);
        #pragma unroll
        for (int e=0; e<8; e++){
          float val = (float)h00[e]*w00 + (float)h01[e]*w01 + (float)h10[e]*w10 + (float)h11[e]*w11;
          prod[e] = (p == 0) ? val : prod[e]*val;
        }
      }
      short8 pk8;
      #pragma unroll
      for (int e=0; e<8; e++) pk8[e] = (short)f2h(prod[e]);
      int byt = (pt*512 + (s*32 + v*8)*2) ^ ((pt & 7) << 4);
      *(short8*)((char*)Xb[0] + byt) = pk8;
    }
  } else {
    #pragma unroll
    for (int i=0; i<3; i++){
      int id = tid + i*256;
      int row = id / 12, sub = id - row*12;
      short8 v = *(const short8*)(feats + (size_t)(n0+row)*96 + sub*8);
      int byt = (row*512 + sub*16) ^ ((row & 7) << 4);
      *(short8*)((char*)Xb[0] + byt) = v;
    }
  }
  __syncthreads();

  floatx4 acc[4][4];
  floatx4 binit[4];
  u32 pk[4][4][2];
  int cur = 0;

  // ---- L0: K=96.  read buf0 -> write buf1
  load_binit(l0_b, wb, lg, binit);
  mm_tile<3>(Xb[0], l0T, ftbase, lane, binit, acc);
  {
    char* Xw = (char*)Xb[1];
    #pragma unroll
    for (int rf=0; rf<4; rf++){
      int fby = (wb + rf*16 + lg*4)*2;
      #pragma unroll
      for (int cf=0; cf<4; cf++){
        int pt = cf*16 + lr;
        u32 p0 = pkrtz(acc[rf][cf][0], acc[rf][cf][1]);
        u32 p1 = pkrtz(acc[rf][cf][2], acc[rf][cf][3]);
        pk[rf][cf][0] = p0; pk[rf][cf][1] = p1;
        int byt = (pt*512 + fby) ^ ((pt & 7) << 4);
        *(u32x2*)(Xw + byt) = (u32x2){p0, p1};
      }
    }
  }
  __syncthreads();
  cur = 1;

  // ---- 3 ResBlocks
  for (int rb=0; rb<3; rb++){
    const u16* W0 = resT + (size_t)(rb*3+0)*65536;
    const u16* W1 = resT + (size_t)(rb*3+1)*65536;
    const u16* W2 = resT + (size_t)(rb*3+2)*65536;
    const float* b0 = res_b + (rb*3+0)*256;
    const float* b1 = res_b + (rb*3+1)*256;
    const float* b2 = res_b + (rb*3+2)*256;

    load_binit(b0, wb, lg, binit);
    mm_tile<8>(Xb[cur], W0, ftbase, lane, binit, acc);
    {
      char* Xw = (char*)Xb[cur^1];
      #pragma unroll
      for (int rf=0; rf<4; rf++){
        int fby = (wb + rf*16 + lg*4)*2;
        #pragma unroll
        for (int cf=0; cf<4; cf++){
          int pt = cf*16 + lr;
          u32 p0 = pkadd(pk[rf][cf][0], pkmax0(pkrtz(acc[rf][cf][0], acc[rf][cf][1])));
          u32 p1 = pkadd(pk[rf][cf][1], pkmax0(pkrtz(acc[rf][cf][2], acc[rf][cf][3])));
          pk[rf][cf][0] = p0; pk[rf][cf][1] = p1;   // pk now holds res
          int byt = (pt*512 + fby) ^ ((pt & 7) << 4);
          *(u32x2*)(Xw + byt) = (u32x2){p0, p1};
        }
      }
    }
    __syncthreads();
    cur ^= 1;

    load_binit(b1, wb, lg, binit);
    mm_tile<8>(Xb[cur], W1, ftbase, lane, binit, acc);
    {
      char* Xw = (char*)Xb[cur^1];
      #pragma unroll
      for (int rf=0; rf<4; rf++){
        int fby = (wb + rf*16 + lg*4)*2;
        #pragma unroll
        for (int cf=0; cf<4; cf++){
          int pt = cf*16 + lr;
          u32 p0 = pkmax0(pkrtz(acc[rf][cf][0], acc[rf][cf][1]));
          u32 p1 = pkmax0(pkrtz(acc[rf][cf][2], acc[rf][cf][3]));
          int byt = (pt*512 + fby) ^ ((pt & 7) << 4);
          *(u32x2*)(Xw + byt) = (u32x2){p0, p1};
        }
      }
    }
    __syncthreads();
    cur ^= 1;

    load_binit(b2, wb, lg, binit);
    mm_tile<8>(Xb[cur], W2, ftbase, lane, binit, acc);
    {
      char* Xw = (char*)Xb[cur^1];
      #pragma unroll
      for (int rf=0; rf<4; rf++){
        int fby = (wb + rf*16 + lg*4)*2;
        #pragma unroll
        for (int cf=0; cf<4; cf++){
          int pt = cf*16 + lr;
          u32 p0 = pkadd(pkmax0(pkrtz(acc[rf][cf][0], acc[rf][cf][1])), pk[rf][cf][0]);
          u32 p1 = pkadd(pkmax0(pkrtz(acc[rf][cf][2], acc[rf][cf][3])), pk[rf][cf][1]);
          pk[rf][cf][0] = p0; pk[rf][cf][1] = p1;   // pk now holds new x
          int byt = (pt*512 + fby) ^ ((pt & 7) << 4);
          *(u32x2*)(Xw + byt) = (u32x2){p0, p1};
        }
      }
    }
    __syncthreads();
    cur ^= 1;
  }

  // ---- final: 256 -> 16, sigmoid. Wave w: points w*16..w*16+15, 16 feats.
  floatx4 accf;
  {
    float4 bo = *(const float4*)(l1_b + lg*4);
    accf = (floatx4){bo.x, bo.y, bo.z, bo.w};
  }
  const char* Xr = (const char*)Xb[cur];
  #pragma unroll 1
  for (int ks=0; ks<8; ks++){
    int pt = wave*16 + lr;
    int byt = (pt*512 + (ks*32 + lg*8)*2) ^ ((pt&7)<<4);
    half8 x = *(const half8*)(Xr + byt);
    half8 w = *(const half8*)(l1T + ((size_t)ks*64 + lane)*8);
    accf = __builtin_amdgcn_mfma_f32_16x16x32_f16(w, x, accf, 0, 0, 0);
  }
  {
    float4 o;
    o.x = 1.0f / (1.0f + __expf(-accf[0]));
    o.y = 1.0f / (1.0f + __expf(-accf[1]));
    o.z = 1.0f / (1.0f + __expf(-accf[2]));
    o.w = 1.0f / (1.0f + __expf(-accf[3]));
    *(float4*)(out + (size_t)(n0 + wave*16 + lr)*16 + lg*4) = o;
  }
}

// ---------------- host
extern "C" void kernel_launch(void* const* d_in, const int* in_sizes, int n_in,
                              void* d_out, int out_size, void* d_ws, size_t ws_size,
                              hipStream_t stream)
{
  const float* pts  = (const float*)d_in[0];
  const float* aabb = (const float*)d_in[1];
  const float* l0_w = (const float*)d_in[11];
  const float* res_w= (const float*)d_in[13];
  const float* l1_w = (const float*)d_in[15];
  const float* l0_b = (const float*)d_in[12];
  const float* res_b= (const float*)d_in[14];
  const float* l1_b = (const float*)d_in[16];
  const int N = in_sizes[0] / 3;

  char* ws = (char*)d_ws;
  const size_t woff_l0  = 0;                          // 256*96*2
  const size_t woff_res = 49152;                      // 9*65536*2
  const size_t woff_l1  = woff_res + 9*65536*2;       // 16*256*2
  const size_t foff     = woff_l1 + 8192;             // fallback feats: N*96*2
  const size_t poff     = foff + (size_t)N*96*2;      // f16 planes

  static const int HWs[3] = {128*128, 256*256, 512*512};
  size_t pel[9]; size_t tot = 0;
  for (int s=0;s<3;s++) for (int p=0;p<3;p++){ pel[s*3+p] = tot; tot += (size_t)HWs[s]*32; }

  const bool tr_mode = (ws_size >= poff + tot*2);

  // all weights -> fragment-ordered f16, one launch
  wconv_all_kernel<<<(24576+589824+4096+255)/256, 256, 0, stream>>>(
      l0_w, res_w, l1_w, (u16*)(ws+woff_l0), (u16*)(ws+woff_res), (u16*)(ws+woff_l1));

  PlanePtrs pp;
  if (tr_mode){
    u16* pbase = (u16*)(ws + poff);
    PtransArgs pa;
    int b0 = 0;
    for (int i=0;i<9;i++){
      int s = i/3;
      pa.src[i] = (const float*)d_in[2+i];
      pa.dst[i] = pbase + pel[i];
      pa.blk0[i] = b0;
      pa.HW[i] = HWs[s];
      b0 += HWs[s]/256;
      pp.p[i] = pbase + pel[i];
    }
    pa.blk0[9] = b0;
    ptrans_all_kernel<<<b0, 256, 0, stream>>>(pa);
    mlp_kernel<true><<<N/64, 256, 0, stream>>>(pts, aabb, pp, (const u16*)nullptr,
        (const u16*)(ws+woff_l0), (const u16*)(ws+woff_res), (const u16*)(ws+woff_l1),
        l0_b, res_b, l1_b, (float*)d_out);
  } else {
    for (int i=0;i<9;i++) pp.p[i] = d_in[2+i];
    interp_fb_kernel<<<(N+255)/256, 256, 0, stream>>>(pts, aabb, pp, (u16*)(ws+foff), N);
    mlp_kernel<false><<<N/64, 256, 0, stream>>>(pts, aabb, pp, (const u16*)(ws+foff),
        (const u16*)(ws+woff_l0), (const u16*)(ws+woff_res), (const u16*)(ws+woff_l1),
        l0_b, res_b, l1_b, (float*)d_out);
  }
}

// Round 10
// 223.893 us; speedup vs baseline: 4.6454x; 1.1268x over previous
//
#include <hip/hip_runtime.h>

typedef unsigned short u16;
typedef unsigned int u32;
typedef __attribute__((ext_vector_type(2))) unsigned int u32x2;
typedef __attribute__((ext_vector_type(8))) short short8;
typedef __attribute__((ext_vector_type(8))) _Float16 half8;
typedef __attribute__((ext_vector_type(2))) __fp16 fp16x2;
typedef __attribute__((ext_vector_type(4))) float floatx4;

__device__ __forceinline__ u16 f2h(float f){ _Float16 h = (_Float16)f; return __builtin_bit_cast(u16, h); }
__device__ __forceinline__ u32 pkrtz(float a, float b){
  fp16x2 h = __builtin_amdgcn_cvt_pkrtz(a, b);
  return __builtin_bit_cast(u32, h);
}
// packed f16 relu / add (VOP3P)
__device__ __forceinline__ u32 pkmax0(u32 a){
  u32 d, z = 0;
  asm("v_pk_max_f16 %0, %1, %2" : "=v"(d) : "v"(a), "v"(z));
  return d;
}
__device__ __forceinline__ u32 pkadd(u32 a, u32 b){
  u32 d;
  asm("v_pk_add_f16 %0, %1, %2" : "=v"(d) : "v"(a), "v"(b));
  return d;
}

struct PlanePtrs { const void* p[9]; };
struct PtransArgs { const float* src[9]; u16* dst[9]; int blk0[10]; int HW[9]; };

// ---------------- prep: all 9 plane transposes in one launch
// [C=32][HW] f32 -> [HW][C] f16
__global__ void ptrans_all_kernel(PtransArgs a){
  __shared__ float tile[32][257];
  int bi = blockIdx.x;
  int i = 0;
  #pragma unroll
  for (int k = 1; k < 9; k++) if (bi >= a.blk0[k]) i = k;
  const float* src = a.src[i];
  u16* dst = a.dst[i];
  const int HW = a.HW[i];
  const int t = threadIdx.x;
  const size_t hw0 = (size_t)(bi - a.blk0[i]) * 256;
  #pragma unroll
  for (int c = 0; c < 32; c++) tile[c][t] = src[(size_t)c*HW + hw0 + t];
  __syncthreads();
  u32* d32 = (u32*)(dst + hw0*32);
  #pragma unroll
  for (int k = 0; k < 16; k++){
    int idx = k*512 + t*2;
    int j = idx >> 5, cc = idx & 31;
    u32 lo = f2h(tile[cc][j]);
    u32 hi = f2h(tile[cc+1][j]);
    d32[k*256 + t] = lo | (hi << 16);
  }
}

// ---------------- prep: all weights -> MFMA A-fragment order f16, one launch
// Logical A[of][k] = src[m][k][of]; stored dst[m][ft][ks][lane][e]:
//   of = ft*16 + (lane&15), k = ks*32 + (lane>>4)*8 + e
__device__ __forceinline__ void wconv_one(const float* src, u16* dst, int fin, int fout, int t){
  int per = fin * fout;
  int m = t / per, r = t - m*per;
  int KS = fin >> 5;
  int e = r & 7;
  int lane = (r >> 3) & 63;
  int fs = r >> 9;
  int ks = fs % KS, ft = fs / KS;
  int of = ft*16 + (lane & 15);
  int k  = ks*32 + (lane >> 4)*8 + e;
  dst[t] = f2h(src[(size_t)m*per + (size_t)k*fout + of]);
}
__global__ void wconv_all_kernel(const float* l0_w, const float* res_w, const float* l1_w,
                                 u16* l0T, u16* resT, u16* l1T){
  int t = blockIdx.x*256 + threadIdx.x;           // total 24576 + 589824 + 4096
  if (t < 24576){ wconv_one(l0_w, l0T, 96, 256, t); return; }
  t -= 24576;
  if (t < 589824){ wconv_one(res_w, resT, 256, 256, t); return; }
  t -= 589824;
  if (t < 4096){ wconv_one(l1_w, l1T, 256, 16, t); }
}

// ---------------- standalone interp fallback (untransposed planes -> feats)
__global__ void interp_fb_kernel(const float* __restrict__ pts, const float* __restrict__ aabb,
                                 PlanePtrs pp, u16* __restrict__ feats, int N)
{
  int n = blockIdx.x*256 + threadIdx.x;
  if (n >= N) return;
  float xn[3];
  #pragma unroll
  for (int d=0; d<3; d++){
    float lo = aabb[d], hi = aabb[3+d];
    xn[d] = (pts[(size_t)n*3 + d] - lo) * (2.0f/(hi - lo)) - 1.0f;
  }
  const int c0s[3] = {0,0,1};
  const int c1s[3] = {1,2,2};
  #pragma unroll
  for (int s=0; s<3; s++){
    const int R = 128 << s;
    float prod[32];
    #pragma unroll
    for (int p=0; p<3; p++){
      float fx = (xn[c0s[p]] + 1.0f) * 0.5f * (float)(R-1);
      float fy = (xn[c1s[p]] + 1.0f) * 0.5f * (float)(R-1);
      float fx0 = fminf(fmaxf(floorf(fx), 0.0f), (float)(R-2));
      float fy0 = fminf(fmaxf(floorf(fy), 0.0f), (float)(R-2));
      int x0 = (int)fx0, y0 = (int)fy0;
      float wx = fx - fx0, wy = fy - fy0;
      float w00 = (1.0f-wx)*(1.0f-wy), w01 = wx*(1.0f-wy);
      float w10 = (1.0f-wx)*wy,        w11 = wx*wy;
      const size_t HW = (size_t)R*R;
      const float* b00f = (const float*)pp.p[s*3+p] + (size_t)y0*R + x0;
      #pragma unroll 4
      for (int c=0; c<32; c++){
        const float* q = b00f + (size_t)c*HW;
        float val = q[0]*w00 + q[1]*w01 + q[R]*w10 + q[R+1]*w11;
        prod[c] = (p == 0) ? val : prod[c]*val;
      }
    }
    #pragma unroll
    for (int vv=0; vv<4; vv++){
      short8 pk8;
      #pragma unroll
      for (int e=0; e<8; e++) pk8[e] = (short)f2h(prod[vv*8+e]);
      *(short8*)(feats + (size_t)n*96 + s*32 + vv*8) = pk8;
    }
  }
}

// ---------------- fused gather + MLP (fp16 MFMA, A=weights B=activations^T)
// X (single 32KB buffer) holds activations [64 points][256 feat] f16,
//   byte addr = (pt*512 + feat*2) ^ ((pt&7)<<4)
// 2 barriers/layer (read-drain + write-publish); single buffer buys
// 3 blocks/CU at launch_bounds(256,3): 92 arch + 64 acc = 156 <= 512/3.
// Bias folded into acc init. ks loop NOT unrolled (R3/R4 over-unroll spilled).
template<int KSTEPS>
__device__ __forceinline__ void mm_tile(const u16* X, const u16* __restrict__ WTs,
                                        int ftbase, int lane, const floatx4 binit[4],
                                        floatx4 acc[4][4])
{
  const int lr = lane & 15, lg = lane >> 4;
  #pragma unroll
  for (int rf=0; rf<4; rf++)
    #pragma unroll
    for (int cf=0; cf<4; cf++)
      acc[rf][cf] = binit[rf];
  #pragma unroll 1
  for (int ks=0; ks<KSTEPS; ks++){
    half8 w[4];
    #pragma unroll
    for (int rf=0; rf<4; rf++)
      w[rf] = *(const half8*)(WTs + ((size_t)((ftbase+rf)*KSTEPS + ks)*64 + lane)*8);
    half8 x[4];
    #pragma unroll
    for (int cf=0; cf<4; cf++){
      int pt = cf*16 + lr;
      int byt = (pt*512 + (ks*32 + lg*8)*2) ^ ((pt & 7) << 4);
      x[cf] = *(const half8*)((const char*)X + byt);
    }
    __builtin_amdgcn_s_setprio(1);
    #pragma unroll
    for (int rf=0; rf<4; rf++)
      #pragma unroll
      for (int cf=0; cf<4; cf++)
        acc[rf][cf] = __builtin_amdgcn_mfma_f32_16x16x32_f16(w[rf], x[cf], acc[rf][cf], 0, 0, 0);
    __builtin_amdgcn_s_setprio(0);
  }
}

__device__ __forceinline__ void load_binit(const float* b, int wb, int lg, floatx4* bi){
  #pragma unroll
  for (int rf=0; rf<4; rf++){
    float4 v = *(const float4*)(b + wb + rf*16 + lg*4);
    bi[rf] = (floatx4){v.x, v.y, v.z, v.w};
  }
}

template<bool GATHER>
__global__ __launch_bounds__(256, 3) void mlp_kernel(
    const float* __restrict__ pts, const float* __restrict__ aabb, PlanePtrs pp,
    const u16* __restrict__ feats,
    const u16* __restrict__ l0T, const u16* __restrict__ resT, const u16* __restrict__ l1T,
    const float* __restrict__ l0_b, const float* __restrict__ res_b, const float* __restrict__ l1_b,
    float* __restrict__ out)
{
  __shared__ u16 X[64*256];
  const int tid = threadIdx.x;
  const int wave = tid >> 6, lane = tid & 63;
  const int lr = lane & 15, lg = lane >> 4;
  const int n0 = blockIdx.x * 64;
  const int ftbase = wave * 4;
  const int wb = wave * 64;

  if constexpr (GATHER){
    // ---- fused interp: 4 threads/point, thread (pt, v) -> channels v*8..v*8+7
    const int pt = tid >> 2, v = tid & 3;
    const int n = n0 + pt;
    float xn[3];
    #pragma unroll
    for (int d=0; d<3; d++){
      float lo = aabb[d], hi = aabb[3+d];
      xn[d] = (pts[(size_t)n*3 + d] - lo) * (2.0f/(hi - lo)) - 1.0f;
    }
    const int c0s[3] = {0,0,1};
    const int c1s[3] = {1,2,2};
    #pragma unroll
    for (int s=0; s<3; s++){
      const int R = 128 << s;
      float prod[8];
      #pragma unroll
      for (int p=0; p<3; p++){
        float fx = (xn[c0s[p]] + 1.0f) * 0.5f * (float)(R-1);
        float fy = (xn[c1s[p]] + 1.0f) * 0.5f * (float)(R-1);
        float fx0 = fminf(fmaxf(floorf(fx), 0.0f), (float)(R-2));
        float fy0 = fminf(fmaxf(floorf(fy), 0.0f), (float)(R-2));
        int x0 = (int)fx0, y0 = (int)fy0;
        float wx = fx - fx0, wy = fy - fy0;
        float w00 = (1.0f-wx)*(1.0f-wy), w01 = wx*(1.0f-wy);
        float w10 = (1.0f-wx)*wy,        w11 = wx*wy;
        const u16* base = (const u16*)pp.p[s*3 + p];
        const u16* b00 = base + ((size_t)y0*R + x0)*32 + v*8;
        const u16* b10 = b00 + (size_t)R*32;
        half8 h00 = *(const half8*)b00;
        half8 h01 = *(const half8*)(b00 + 32);
        half8 h10 = *(const half8*)b10;
        half8 h11 = *(const half8*)(b10 + 32);
        #pragma unroll
        for (int e=0; e<8; e++){
          float val = (float)h00[e]*w00 + (float)h01[e]*w01 + (float)h10[e]*w10 + (float)h11[e]*w11;
          prod[e] = (p == 0) ? val : prod[e]*val;
        }
      }
      short8 pk8;
      #pragma unroll
      for (int e=0; e<8; e++) pk8[e] = (short)f2h(prod[e]);
      int byt = (pt*512 + (s*32 + v*8)*2) ^ ((pt & 7) << 4);
      *(short8*)((char*)X + byt) = pk8;
    }
  } else {
    #pragma unroll
    for (int i=0; i<3; i++){
      int id = tid + i*256;
      int row = id / 12, sub = id - row*12;
      short8 v = *(const short8*)(feats + (size_t)(n0+row)*96 + sub*8);
      int byt = (row*512 + sub*16) ^ ((row & 7) << 4);
      *(short8*)((char*)X + byt) = v;
    }
  }
  __syncthreads();

  floatx4 acc[4][4];
  floatx4 binit[4];
  u32 pk[4][4][2];

  // ---- L0: K=96
  load_binit(l0_b, wb, lg, binit);
  mm_tile<3>(X, l0T, ftbase, lane, binit, acc);
  __syncthreads();
  #pragma unroll
  for (int rf=0; rf<4; rf++){
    int fby = (wb + rf*16 + lg*4)*2;
    #pragma unroll
    for (int cf=0; cf<4; cf++){
      int pt = cf*16 + lr;
      u32 p0 = pkrtz(acc[rf][cf][0], acc[rf][cf][1]);
      u32 p1 = pkrtz(acc[rf][cf][2], acc[rf][cf][3]);
      pk[rf][cf][0] = p0; pk[rf][cf][1] = p1;
      int byt = (pt*512 + fby) ^ ((pt & 7) << 4);
      *(u32x2*)((char*)X + byt) = (u32x2){p0, p1};
    }
  }
  __syncthreads();

  // ---- 3 ResBlocks; each layer: mm_tile -> barrier -> write -> barrier
  for (int rb=0; rb<3; rb++){
    const u16* W0 = resT + (size_t)(rb*3+0)*65536;
    const u16* W1 = resT + (size_t)(rb*3+1)*65536;
    const u16* W2 = resT + (size_t)(rb*3+2)*65536;
    const float* b0 = res_b + (rb*3+0)*256;
    const float* b1 = res_b + (rb*3+1)*256;
    const float* b2 = res_b + (rb*3+2)*256;

    load_binit(b0, wb, lg, binit);
    mm_tile<8>(X, W0, ftbase, lane, binit, acc);
    __syncthreads();
    #pragma unroll
    for (int rf=0; rf<4; rf++){
      int fby = (wb + rf*16 + lg*4)*2;
      #pragma unroll
      for (int cf=0; cf<4; cf++){
        int pt = cf*16 + lr;
        u32 p0 = pkadd(pk[rf][cf][0], pkmax0(pkrtz(acc[rf][cf][0], acc[rf][cf][1])));
        u32 p1 = pkadd(pk[rf][cf][1], pkmax0(pkrtz(acc[rf][cf][2], acc[rf][cf][3])));
        pk[rf][cf][0] = p0; pk[rf][cf][1] = p1;   // pk now holds res
        int byt = (pt*512 + fby) ^ ((pt & 7) << 4);
        *(u32x2*)((char*)X + byt) = (u32x2){p0, p1};
      }
    }
    __syncthreads();

    load_binit(b1, wb, lg, binit);
    mm_tile<8>(X, W1, ftbase, lane, binit, acc);
    __syncthreads();
    #pragma unroll
    for (int rf=0; rf<4; rf++){
      int fby = (wb + rf*16 + lg*4)*2;
      #pragma unroll
      for (int cf=0; cf<4; cf++){
        int pt = cf*16 + lr;
        u32 p0 = pkmax0(pkrtz(acc[rf][cf][0], acc[rf][cf][1]));
        u32 p1 = pkmax0(pkrtz(acc[rf][cf][2], acc[rf][cf][3]));
        int byt = (pt*512 + fby) ^ ((pt & 7) << 4);
        *(u32x2*)((char*)X + byt) = (u32x2){p0, p1};
      }
    }
    __syncthreads();

    load_binit(b2, wb, lg, binit);
    mm_tile<8>(X, W2, ftbase, lane, binit, acc);
    __syncthreads();
    #pragma unroll
    for (int rf=0; rf<4; rf++){
      int fby = (wb + rf*16 + lg*4)*2;
      #pragma unroll
      for (int cf=0; cf<4; cf++){
        int pt = cf*16 + lr;
        u32 p0 = pkadd(pkmax0(pkrtz(acc[rf][cf][0], acc[rf][cf][1])), pk[rf][cf][0]);
        u32 p1 = pkadd(pkmax0(pkrtz(acc[rf][cf][2], acc[rf][cf][3])), pk[rf][cf][1]);
        pk[rf][cf][0] = p0; pk[rf][cf][1] = p1;   // pk now holds new x
        int byt = (pt*512 + fby) ^ ((pt & 7) << 4);
        *(u32x2*)((char*)X + byt) = (u32x2){p0, p1};
      }
    }
    __syncthreads();
  }

  // ---- final: 256 -> 16, sigmoid. Wave w: points w*16..w*16+15, 16 feats.
  floatx4 accf;
  {
    float4 bo = *(const float4*)(l1_b + lg*4);
    accf = (floatx4){bo.x, bo.y, bo.z, bo.w};
  }
  #pragma unroll 1
  for (int ks=0; ks<8; ks++){
    int pt = wave*16 + lr;
    int byt = (pt*512 + (ks*32 + lg*8)*2) ^ ((pt&7)<<4);
    half8 x = *(const half8*)((const char*)X + byt);
    half8 w = *(const half8*)(l1T + ((size_t)ks*64 + lane)*8);
    accf = __builtin_amdgcn_mfma_f32_16x16x32_f16(w, x, accf, 0, 0, 0);
  }
  {
    float4 o;
    o.x = 1.0f / (1.0f + __expf(-accf[0]));
    o.y = 1.0f / (1.0f + __expf(-accf[1]));
    o.z = 1.0f / (1.0f + __expf(-accf[2]));
    o.w = 1.0f / (1.0f + __expf(-accf[3]));
    *(float4*)(out + (size_t)(n0 + wave*16 + lr)*16 + lg*4) = o;
  }
}

// ---------------- host
extern "C" void kernel_launch(void* const* d_in, const int* in_sizes, int n_in,
                              void* d_out, int out_size, void* d_ws, size_t ws_size,
                              hipStream_t stream)
{
  const float* pts  = (const float*)d_in[0];
  const float* aabb = (const float*)d_in[1];
  const float* l0_w = (const float*)d_in[11];
  const float* res_w= (const float*)d_in[13];
  const float* l1_w = (const float*)d_in[15];
  const float* l0_b = (const float*)d_in[12];
  const float* res_b= (const float*)d_in[14];
  const float* l1_b = (const float*)d_in[16];
  const int N = in_sizes[0] / 3;

  char* ws = (char*)d_ws;
  const size_t woff_l0  = 0;                          // 256*96*2
  const size_t woff_res = 49152;                      // 9*65536*2
  const size_t woff_l1  = woff_res + 9*65536*2;       // 16*256*2
  const size_t foff     = woff_l1 + 8192;             // fallback feats: N*96*2
  const size_t poff     = foff + (size_t)N*96*2;      // f16 planes

  static const int HWs[3] = {128*128, 256*256, 512*512};
  size_t pel[9]; size_t tot = 0;
  for (int s=0;s<3;s++) for (int p=0;p<3;p++){ pel[s*3+p] = tot; tot += (size_t)HWs[s]*32; }

  const bool tr_mode = (ws_size >= poff + tot*2);

  // all weights -> fragment-ordered f16, one launch
  wconv_all_kernel<<<(24576+589824+4096+255)/256, 256, 0, stream>>>(
      l0_w, res_w, l1_w, (u16*)(ws+woff_l0), (u16*)(ws+woff_res), (u16*)(ws+woff_l1));

  PlanePtrs pp;
  if (tr_mode){
    u16* pbase = (u16*)(ws + poff);
    PtransArgs pa;
    int b0 = 0;
    for (int i=0;i<9;i++){
      int s = i/3;
      pa.src[i] = (const float*)d_in[2+i];
      pa.dst[i] = pbase + pel[i];
      pa.blk0[i] = b0;
      pa.HW[i] = HWs[s];
      b0 += HWs[s]/256;
      pp.p[i] = pbase + pel[i];
    }
    pa.blk0[9] = b0;
    ptrans_all_kernel<<<b0, 256, 0, stream>>>(pa);
    mlp_kernel<true><<<N/64, 256, 0, stream>>>(pts, aabb, pp, (const u16*)nullptr,
        (const u16*)(ws+woff_l0), (const u16*)(ws+woff_res), (const u16*)(ws+woff_l1),
        l0_b, res_b, l1_b, (float*)d_out);
  } else {
    for (int i=0;i<9;i++) pp.p[i] = d_in[2+i];
    interp_fb_kernel<<<(N+255)/256, 256, 0, stream>>>(pts, aabb, pp, (u16*)(ws+foff), N);
    mlp_kernel<false><<<N/64, 256, 0, stream>>>(pts, aabb, pp, (const u16*)(ws+foff),
        (const u16*)(ws+woff_l0), (const u16*)(ws+woff_res), (const u16*)(ws+woff_l1),
        l0_b, res_b, l1_b, (float*)d_out);
  }
}